// Round 1
// baseline (2362.293 us; speedup 1.0000x reference)
//
#include <hip/hip_runtime.h>

typedef __attribute__((ext_vector_type(8))) short bf16x8;
typedef __attribute__((ext_vector_type(4))) float f32x4;
typedef __attribute__((ext_vector_type(4))) int   i32x4;

#define PI_F 3.14159265358979323846f

// ---------- constants ----------
// B=8, C=256, H=W=128, M=7
#define NB 8
#define NC 256
#define NH 128
#define NW 128
#define IMG 16384           // H*W
#define NIMG 2048           // B*C
#define LST 129             // LDS row stride (floats) for 128x128 planes

__device__ __forceinline__ unsigned short f2bf(float f){
  unsigned int u = __float_as_uint(f);
  u += 0x7FFFu + ((u >> 16) & 1u);
  return (unsigned short)(u >> 16);
}

// =====================================================================
// K_center: per image, compute |X[u,v]| (ortho) for u,v in {-3..3}
// (unshifted freqs == the 7x7 center of the shifted spectrum).
// Writes magC[img][49].
// =====================================================================
__global__ void __launch_bounds__(128) K_center(const float* __restrict__ xlow,
                                                float* __restrict__ magC){
  __shared__ float gre[128*7];
  __shared__ float gim[128*7];
  __shared__ float twc[128];
  __shared__ float tws[128];
  const int tid = threadIdx.x;
  const int img = blockIdx.x;

  { // twiddle table e^{-2pi i q/128} stored as (cos, sin) positive
    float th = (float)tid * (2.0f*PI_F/128.0f);
    twc[tid] = cosf(th); tws[tid] = sinf(th);
  }
  __syncthreads();

  // phase 1: row DFT at 7 column-frequencies v = -3..3
  {
    const int r = tid;
    const float4* rowp = (const float4*)(xlow + (size_t)img*IMG + (size_t)r*NW);
    float aR[7], aI[7]; int q[7];
    #pragma unroll
    for (int v=0; v<7; ++v){ aR[v]=0.f; aI[v]=0.f; q[v]=0; }
    for (int c4=0; c4<32; ++c4){
      float4 xv4 = rowp[c4];
      float xs4[4] = {xv4.x, xv4.y, xv4.z, xv4.w};
      #pragma unroll
      for (int e=0; e<4; ++e){
        float xv = xs4[e];
        #pragma unroll
        for (int v=0; v<7; ++v){
          float c = twc[q[v]], s = tws[q[v]];
          aR[v] += xv * c;
          aI[v] -= xv * s;
          q[v] += (v-3); q[v] &= 127;
        }
      }
    }
    #pragma unroll
    for (int v=0; v<7; ++v){ gre[r*7+v] = aR[v]; gim[r*7+v] = aI[v]; }
  }
  __syncthreads();

  // phase 2: column DFT at 7 row-frequencies u = -3..3 ; write |X|/128
  if (tid < 49){
    int a = tid / 7, d = tid % 7;
    int u = a - 3;
    float xr = 0.f, xi = 0.f; int q = 0;
    for (int r=0; r<128; ++r){
      float gr = gre[r*7+d], gi = gim[r*7+d];
      float c = twc[q], s = tws[q];
      xr += gr*c + gi*s;
      xi += gi*c - gr*s;
      q = (q + u) & 127;
    }
    magC[(size_t)img*49 + tid] = sqrtf(xr*xr + xi*xi) * (1.0f/128.0f);
  }
}

// =====================================================================
// K_mlp: per batch: mean over channels of magC -> MLP -> anisotropic
// 7x7 kernel (normalized). Deterministic (no atomics).
// =====================================================================
__global__ void __launch_bounds__(64) K_mlp(const float* __restrict__ magC,
                                            const float* __restrict__ w1,
                                            const float* __restrict__ b1,
                                            const float* __restrict__ w2,
                                            const float* __restrict__ b2,
                                            float* __restrict__ kern){
  __shared__ float flat[49];
  __shared__ float hh[32];
  const int b = blockIdx.x, tid = threadIdx.x;
  if (tid < 49){
    float s = 0.f;
    for (int c=0; c<256; ++c) s += magC[((size_t)b*256 + c)*49 + tid];
    flat[tid] = s * (1.0f/256.0f);
  }
  __syncthreads();
  if (tid < 32){
    float s = b1[tid];
    for (int i=0; i<49; ++i) s += flat[i]*w1[tid*49+i];
    hh[tid] = fmaxf(s, 0.f);
  }
  __syncthreads();
  if (tid == 0){
    float p[3];
    #pragma unroll
    for (int k=0; k<3; ++k){
      float s = b2[k];
      for (int j=0; j<32; ++j) s += hh[j]*w2[k*32+j];
      p[k] = s;
    }
    float theta = atan2f(p[0], p[1])*0.5f + 1.57079632679489662f;
    float ct = cosf(theta), st = sinf(theta);
    float l1 = expf(p[2]);
    float l2 = 1.0f/(l1 + 1e-8f);
    float inv1 = 1.0f/(2.0f*l1*l1);
    float inv2 = 1.0f/(2.0f*l2*l2);
    float sum = 0.f;
    for (int i=0; i<7; ++i) for (int j=0; j<7; ++j){
      float yy = (float)(i-3), xx = (float)(j-3);
      float xr =  xx*ct + yy*st;
      float yr = -xx*st + yy*ct;
      sum += expf(-(xr*xr*inv1 + yr*yr*inv2));
    }
    float inv = 1.0f/(sum + 1e-8f);
    for (int i=0; i<7; ++i) for (int j=0; j<7; ++j){
      float yy = (float)(i-3), xx = (float)(j-3);
      float xr =  xx*ct + yy*st;
      float yr = -xx*st + yy*ct;
      kern[b*49 + i*7 + j] = expf(-(xr*xr*inv1 + yr*yr*inv2)) * inv;
    }
  }
}

// =====================================================================
// K_w: refine_w f32 -> bf16
// =====================================================================
__global__ void __launch_bounds__(256) K_w(const float* __restrict__ rw,
                                           unsigned short* __restrict__ rwbf){
  int i = blockIdx.x*256 + threadIdx.x;   // 65536 total
  rwbf[i] = f2bf(rw[i]);
}

// =====================================================================
// wave-level 128-pt FFT: 64 lanes hold elements (lane, lane+64).
// DIF; cross-lane via shfl_xor; bit-reversal fixed at the end.
// tsgn = -1 forward (e^{-i}), +1 inverse (e^{+i}).
// =====================================================================
__device__ __forceinline__ void wfft128(float& x0r, float& x0i,
                                        float& x1r, float& x1i,
                                        const float* stc, const float* sts,
                                        float tsgn, int lane, int rsrc){
  // stage 0: span 64 (both elements in-lane), twiddle W128^lane
  {
    float dr = x0r - x1r, di = x0i - x1i;
    x0r += x1r; x0i += x1i;
    float c = stc[0], s = tsgn * sts[0];
    x1r = dr*c - di*s;
    x1i = dr*s + di*c;
  }
  // stages 1..6 on both 64-length sub-arrays
  #pragma unroll
  for (int s=1; s<=6; ++s){
    const int span = 64 >> s;
    const bool up = (lane & span) != 0;
    const float c = stc[s], si = tsgn * sts[s];
    {
      float pr = __shfl_xor(x0r, span), pi = __shfl_xor(x0i, span);
      float sr = x0r + pr, sj = x0i + pi;
      float er = pr - x0r, ei = pi - x0i;     // lower - upper (for upper lanes)
      float tr = er*c - ei*si, ti = er*si + ei*c;
      x0r = up ? tr : sr; x0i = up ? ti : sj;
    }
    {
      float pr = __shfl_xor(x1r, span), pi = __shfl_xor(x1i, span);
      float sr = x1r + pr, sj = x1i + pi;
      float er = pr - x1r, ei = pi - x1i;
      float tr = er*c - ei*si, ti = er*si + ei*c;
      x1r = up ? tr : sr; x1i = up ? ti : sj;
    }
  }
  // undo bit-reversal: lane l fetches from lane br6(l); then
  // x0 = X[2*lane], x1 = X[2*lane+1]
  x0r = __shfl(x0r, rsrc); x0i = __shfl(x0i, rsrc);
  x1r = __shfl(x1r, rsrc); x1i = __shfl(x1i, rsrc);
}

// =====================================================================
// K_main: per image: FFT2 (with fftshift folded via (-1)^(r+c)),
// 7x7 zero-padded conv on shifted spectrum, IFFT2 (ifftshift folded),
// write real part as bf16.
// =====================================================================
__global__ void __launch_bounds__(512) K_main(const float* __restrict__ xlow,
                                              const float* __restrict__ kern,
                                              unsigned short* __restrict__ filt){
  __shared__ float lre[128*LST];
  __shared__ float lim[128*LST];
  __shared__ float lkk[49];

  const int tid  = threadIdx.x;
  const int lane = tid & 63;
  const int wv   = tid >> 6;          // 0..7
  const int img  = blockIdx.x;
  const int b    = img >> 8;

  if (tid < 49) lkk[tid] = kern[b*49 + tid];

  // per-lane stage twiddles (shared by all phases)
  float stc[7], sts[7];
  {
    float th = (float)lane * (PI_F/64.0f);          // 2pi*lane/128
    stc[0] = cosf(th); sts[0] = sinf(th);
  }
  #pragma unroll
  for (int s=1; s<=6; ++s){
    int span = 64 >> s;
    int e = (lane & (span-1)) * (32/span);          // exponent in W_64 units
    float th = (float)e * (PI_F/32.0f);             // 2pi*e/64
    stc[s] = cosf(th); sts[s] = sinf(th);
  }
  const int rsrc = ((lane&1)<<5)|((lane&2)<<3)|((lane&4)<<1)|((lane&8)>>1)|((lane&16)>>3)|((lane&32)>>5);
  const float invN = 1.0f/128.0f;

  // ---- Phase A: forward row FFTs (global -> LDS), fold (-1)^(r+c)/128
  for (int i=0; i<16; ++i){
    int row = wv*16 + i;
    float v0 = xlow[(size_t)img*IMG + (size_t)row*NW + lane];
    float v1 = xlow[(size_t)img*IMG + (size_t)row*NW + lane + 64];
    float sgn = ((row + lane) & 1) ? -invN : invN;  // (-1)^(row+lane) ; col lane+64 same parity
    float x0r = v0*sgn, x0i = 0.f, x1r = v1*sgn, x1i = 0.f;
    wfft128(x0r,x0i,x1r,x1i, stc,sts, -1.0f, lane, rsrc);
    lre[row*LST + 2*lane  ] = x0r;  lim[row*LST + 2*lane  ] = x0i;
    lre[row*LST + 2*lane+1] = x1r;  lim[row*LST + 2*lane+1] = x1i;
  }
  __syncthreads();

  // ---- Phase B: forward column FFTs (in-place in LDS)
  for (int i=0; i<16; ++i){
    int col = wv*16 + i;
    float x0r = lre[lane*LST + col],      x0i = lim[lane*LST + col];
    float x1r = lre[(lane+64)*LST + col], x1i = lim[(lane+64)*LST + col];
    wfft128(x0r,x0i,x1r,x1i, stc,sts, -1.0f, lane, rsrc);
    lre[(2*lane)*LST   + col] = x0r;  lim[(2*lane)*LST   + col] = x0i;
    lre[(2*lane+1)*LST + col] = x1r;  lim[(2*lane+1)*LST + col] = x1i;
  }
  __syncthreads();

  // ---- Phase C: 7x7 zero-padded conv on (shifted) spectrum, in LDS.
  // 2048 tiles of 2x4; each thread owns 4 tiles; outputs in registers,
  // write back after a barrier (in-place safe).
  float aR[4][2][4], aI[4][2][4];
  #pragma unroll
  for (int t4=0; t4<4; ++t4)
    #pragma unroll
    for (int oi=0; oi<2; ++oi)
      #pragma unroll
      for (int oc=0; oc<4; ++oc){ aR[t4][oi][oc]=0.f; aI[t4][oi][oc]=0.f; }

  #pragma unroll
  for (int t4=0; t4<4; ++t4){
    const int tau = tid + t4*512;
    const int r0 = (tau >> 5) * 2;
    const int c0 = (tau & 31) * 4;
    for (int j=0; j<8; ++j){
      int ir = r0 - 3 + j;
      if ((unsigned)ir > 127u) continue;
      float wre[10], wim[10];
      #pragma unroll
      for (int q=0; q<10; ++q){
        int ic = c0 - 3 + q;
        bool ok = (unsigned)ic < 128u;
        wre[q] = ok ? lre[ir*LST + ic] : 0.f;
        wim[q] = ok ? lim[ir*LST + ic] : 0.f;
      }
      #pragma unroll
      for (int oi=0; oi<2; ++oi){
        int dr = j - oi;
        if ((unsigned)dr > 6u) continue;
        const float* kk = &lkk[dr*7];
        #pragma unroll
        for (int dc=0; dc<7; ++dc){
          float kv = kk[dc];
          #pragma unroll
          for (int oc=0; oc<4; ++oc){
            aR[t4][oi][oc] += kv * wre[oc+dc];
            aI[t4][oi][oc] += kv * wim[oc+dc];
          }
        }
      }
    }
  }
  __syncthreads();
  #pragma unroll
  for (int t4=0; t4<4; ++t4){
    const int tau = tid + t4*512;
    const int r0 = (tau >> 5) * 2;
    const int c0 = (tau & 31) * 4;
    #pragma unroll
    for (int oi=0; oi<2; ++oi)
      #pragma unroll
      for (int oc=0; oc<4; ++oc){
        lre[(r0+oi)*LST + c0+oc] = aR[t4][oi][oc];
        lim[(r0+oi)*LST + c0+oc] = aI[t4][oi][oc];
      }
  }
  __syncthreads();

  // ---- Phase D: inverse column FFTs (in-place)
  for (int i=0; i<16; ++i){
    int col = wv*16 + i;
    float x0r = lre[lane*LST + col],      x0i = lim[lane*LST + col];
    float x1r = lre[(lane+64)*LST + col], x1i = lim[(lane+64)*LST + col];
    wfft128(x0r,x0i,x1r,x1i, stc,sts, +1.0f, lane, rsrc);
    lre[(2*lane)*LST   + col] = x0r;  lim[(2*lane)*LST   + col] = x0i;
    lre[(2*lane+1)*LST + col] = x1r;  lim[(2*lane+1)*LST + col] = x1i;
  }
  __syncthreads();

  // ---- Phase E: inverse row FFTs + (-1)^(r+c)/128 + real part -> bf16
  for (int i=0; i<16; ++i){
    int row = wv*16 + i;
    float x0r = lre[row*LST + lane],      x0i = lim[row*LST + lane];
    float x1r = lre[row*LST + lane + 64], x1i = lim[row*LST + lane + 64];
    wfft128(x0r,x0i,x1r,x1i, stc,sts, +1.0f, lane, rsrc);
    float s0 = (row & 1) ? -invN : invN;    // (-1)^(row + 2*lane) = (-1)^row
    float o0 = x0r * s0;
    float o1 = x1r * (-s0);
    unsigned int pack = ((unsigned int)f2bf(o1) << 16) | (unsigned int)f2bf(o0);
    *(unsigned int*)(&filt[(size_t)img*IMG + (size_t)row*NW + 2*lane]) = pack;
  }
}

// =====================================================================
// K_trans: filt [b][c][p] bf16 -> filtT [b][p][c] bf16 (32x32 tiles)
// =====================================================================
__global__ void __launch_bounds__(256) K_trans(const unsigned short* __restrict__ in,
                                               unsigned short* __restrict__ outT){
  __shared__ unsigned short tile[32][33];
  const int p0 = blockIdx.x * 32;
  const int c0 = blockIdx.y * 32;
  const int b  = blockIdx.z;
  const int tx = threadIdx.x & 31, ty = threadIdx.x >> 5;
  #pragma unroll
  for (int w=0; w<4; ++w){
    int ii = ty + w*8;
    tile[ii][tx] = in[((size_t)b*NC + c0 + ii)*IMG + p0 + tx];
  }
  __syncthreads();
  #pragma unroll
  for (int w=0; w<4; ++w){
    int ii = ty + w*8;
    outT[((size_t)b*IMG + p0 + ii)*NC + c0 + tx] = tile[tx][ii];
  }
}

// =====================================================================
// K_gemm: out[b,o,p] = sum_c rw[o,c]*filt[b,c,p]  (bf16 MFMA, K=256)
//         + bilinear-upsampled x_high epilogue.
// Grid: (p-tile 128, o-tile 2, b 8); block 256 = 4 waves (2x2), 64x64/wave.
// =====================================================================
__global__ void __launch_bounds__(256) K_gemm(const unsigned short* __restrict__ rwbf,
                                              const unsigned short* __restrict__ filtT,
                                              const float* __restrict__ xhigh,
                                              float* __restrict__ out){
  __shared__ unsigned short At[128*32];
  __shared__ unsigned short Bt[128*32];
  const int tid = threadIdx.x, lane = tid & 63, wv = tid >> 6;
  const int wr = wv >> 1, wc = wv & 1;
  const int pt = blockIdx.x, ot = blockIdx.y, b = blockIdx.z;
  const int p0 = pt*128, o0 = ot*128;

  f32x4 acc[4][4];
  #pragma unroll
  for (int m=0;m<4;++m)
    #pragma unroll
    for (int n=0;n<4;++n){ f32x4 z = {0.f,0.f,0.f,0.f}; acc[m][n] = z; }

  const int row  = tid >> 2;
  const int koff = (tid & 3) * 8;

  for (int ks=0; ks<8; ++ks){
    const int k0 = ks*32;
    i32x4 av0 = *(const i32x4*)(&rwbf[(size_t)(o0+row   )*256 + k0 + koff]);
    i32x4 av1 = *(const i32x4*)(&rwbf[(size_t)(o0+row+64)*256 + k0 + koff]);
    i32x4 bv0 = *(const i32x4*)(&filtT[((size_t)b*IMG + p0+row   )*256 + k0 + koff]);
    i32x4 bv1 = *(const i32x4*)(&filtT[((size_t)b*IMG + p0+row+64)*256 + k0 + koff]);
    __syncthreads();
    *(i32x4*)(&At[ row     *32 + koff]) = av0;
    *(i32x4*)(&At[(row+64) *32 + koff]) = av1;
    *(i32x4*)(&Bt[ row     *32 + koff]) = bv0;
    *(i32x4*)(&Bt[(row+64) *32 + koff]) = bv1;
    __syncthreads();

    const int g = lane >> 4, r16 = lane & 15;
    bf16x8 af[4], bfr[4];
    #pragma unroll
    for (int m=0;m<4;++m) af[m]  = *(const bf16x8*)(&At[(wr*64 + m*16 + r16)*32 + g*8]);
    #pragma unroll
    for (int n=0;n<4;++n) bfr[n] = *(const bf16x8*)(&Bt[(wc*64 + n*16 + r16)*32 + g*8]);
    #pragma unroll
    for (int m=0;m<4;++m)
      #pragma unroll
      for (int n=0;n<4;++n)
        acc[m][n] = __builtin_amdgcn_mfma_f32_16x16x32_bf16(af[m], bfr[n], acc[m][n], 0, 0, 0);
  }

  // epilogue: bilinear upsample of x_high (64->128, half-pixel, edge-renorm == clamp)
  const int y = pt;                      // p-tile of 128 == one output row
  float fy = 0.5f*(float)y - 0.25f;
  int iyf = (int)floorf(fy);
  float ty = fy - (float)iyf;
  int iy0 = iyf < 0 ? 0 : iyf;
  int iy1 = (iyf+1) > 63 ? 63 : (iyf+1);
  float wy1 = ty, wy0 = 1.0f - ty;

  const int g = lane >> 4, r16 = lane & 15;
  #pragma unroll
  for (int n=0;n<4;++n){
    int xcol = wc*64 + n*16 + r16;
    float fx = 0.5f*(float)xcol - 0.25f;
    int ixf = (int)floorf(fx);
    float tx = fx - (float)ixf;
    int ix0 = ixf < 0 ? 0 : ixf;
    int ix1 = (ixf+1) > 63 ? 63 : (ixf+1);
    float wx1 = tx, wx0 = 1.0f - tx;
    #pragma unroll
    for (int m=0;m<4;++m){
      #pragma unroll
      for (int j=0;j<4;++j){
        int o = o0 + wr*64 + m*16 + g*4 + j;
        const float* xh = &xhigh[((size_t)b*NC + o)*64*64];
        float up = wy0*(wx0*xh[iy0*64+ix0] + wx1*xh[iy0*64+ix1])
                 + wy1*(wx0*xh[iy1*64+ix0] + wx1*xh[iy1*64+ix1]);
        out[((size_t)b*NC + o)*IMG + (size_t)y*NW + xcol] = acc[m][n][j] + up;
      }
    }
  }
}

// =====================================================================
extern "C" void kernel_launch(void* const* d_in, const int* in_sizes, int n_in,
                              void* d_out, int out_size, void* d_ws, size_t ws_size,
                              hipStream_t stream){
  (void)in_sizes; (void)n_in; (void)out_size; (void)ws_size;
  const float* xhigh = (const float*)d_in[0];
  const float* xlow  = (const float*)d_in[1];
  const float* w1    = (const float*)d_in[2];
  const float* b1    = (const float*)d_in[3];
  const float* w2    = (const float*)d_in[4];
  const float* b2    = (const float*)d_in[5];
  const float* rw    = (const float*)d_in[6];

  char* ws = (char*)d_ws;
  unsigned short* filt  = (unsigned short*)(ws);                       // 67,108,864 B
  unsigned short* filtT = (unsigned short*)(ws + 67108864);            // 67,108,864 B
  float*          magC  = (float*)(ws + 134217728);                    // 401,408 B
  float*          kern  = (float*)(ws + 134217728 + 401408);           // 1,568 B (pad 2048)
  unsigned short* rwbf  = (unsigned short*)(ws + 134217728 + 401408 + 2048); // 131,072 B

  K_center<<<NIMG, 128, 0, stream>>>(xlow, magC);
  K_mlp<<<NB, 64, 0, stream>>>(magC, w1, b1, w2, b2, kern);
  K_w<<<256, 256, 0, stream>>>(rw, rwbf);
  K_main<<<NIMG, 512, 0, stream>>>(xlow, kern, filt);
  K_trans<<<dim3(512, 8, NB), 256, 0, stream>>>(filt, filtT);
  K_gemm<<<dim3(128, 2, NB), 256, 0, stream>>>(rwbf, filtT, xhigh, (float*)d_out);
}

// Round 2
// 473.977 us; speedup vs baseline: 4.9840x; 4.9840x over previous
//
#include <hip/hip_runtime.h>

typedef __attribute__((ext_vector_type(8))) short bf16x8;
typedef __attribute__((ext_vector_type(4))) float f32x4;
typedef __attribute__((ext_vector_type(4))) int   i32x4;

#define PI_F 3.14159265358979323846f
#define C128 0.0490873852123405f      /* 2*pi/128 */
#define INV_SQRT128 0.0883883476483184f
#define INV128 0.0078125f

#define NB 8
#define NC 256
#define NH 128
#define NW 128
#define IMG 16384
#define NIMG 2048

// GH per-image layout (floats, stride 3200):
//  [0..1535]    G  : [w6][re/im][128]   (w = 61..66)
//  [1536..3071] Hh : [z6][re/im][128]   (z = 61..66)
//  [3072..3143] Fc : 36 complex (w6 x z6)
//  [3144..3192] magC: 49
#define GH_STRIDE 3200
// AB per-image layout (floats, stride 3072):
//  [0..1535]    Abar planes [si*2+reim][128]
//  [1536..3071] Bbar rows   [r][ti*2+reim] (12 per row)
#define AB_STRIDE 3072

__device__ __forceinline__ unsigned short f2bf(float f){
  unsigned int u = __float_as_uint(f);
  u += 0x7FFFu + ((u >> 16) & 1u);
  return (unsigned short)(u >> 16);
}
__device__ __forceinline__ float bf2f(unsigned short u){
  return __uint_as_float(((unsigned int)u) << 16);
}

// wrap-pair tables: si=0..5 <-> s=si-3; dp in [pdp0, pdp0+pcnt)
__device__ __constant__ int c_pcnt[6] = {1,2,3,3,2,1};
__device__ __constant__ int c_pdp0[6] = {6,5,4,0,0,0};

// =====================================================================
// K1: per image: high-freq partial DFTs G,Hh + corner Fc + magC(49)
// =====================================================================
__global__ void __launch_bounds__(256) K1(const float* __restrict__ xlow,
                                          float* __restrict__ GH){
  __shared__ unsigned short xs[128*132];
  __shared__ float Hlo[4][2][128];   // z=0..3
  __shared__ float Hhi[4][2][128];   // z=61,62,63,64
  __shared__ float Gg [4][2][128];   // w=61,62,63,64
  __shared__ float twc[128], tws[128];

  const int tid = threadIdx.x;
  const int img = blockIdx.x;
  float* ghb = GH + (size_t)img*GH_STRIDE;

  if (tid < 128){
    float s,c; __sincosf((float)tid*C128, &s, &c);
    twc[tid]=c; tws[tid]=s;
  }
  // load x -> bf16 LDS (stride 132)
  {
    const float4* xp = (const float4*)(xlow + (size_t)img*IMG);
    #pragma unroll
    for (int k=0; k<16; ++k){
      int e4 = k*256 + tid;          // float4 index
      float4 v = xp[e4];
      int px = e4*4;
      int r = px >> 7, c = px & 127;
      ushort4 u; u.x=f2bf(v.x); u.y=f2bf(v.y); u.z=f2bf(v.z); u.w=f2bf(v.w);
      *(ushort4*)(&xs[r*132 + c]) = u;
    }
  }
  __syncthreads();

  // twiddle step constants e^{-2pi i z/128}
  const float w1c= 0.9987954562051724f, w1s=-0.0490676743274180f;
  const float w2c= 0.9951847266721969f, w2s=-0.0980171403295606f;
  const float w3c= 0.9891765099647810f, w3s=-0.1467304744553617f;
  const float v1c=-0.9891765099647810f, v1s=-0.1467304744553617f; // z=61
  const float v2c=-0.9951847266721969f, v2s=-0.0980171403295606f; // z=62
  const float v3c=-0.9987954562051724f, v3s=-0.0490676743274180f; // z=63

  if (tid < 128){
    // row DFT: H_z[r] = sum_c x e^{-2pi i z c/128}, z in {0..3, 61..64}
    const int r = tid;
    const unsigned short* xr = &xs[r*132];
    float h0=0.f, h64=0.f;
    float aR1=0,aI1=0,aR2=0,aI2=0,aR3=0,aI3=0;
    float bR1=0,bI1=0,bR2=0,bI2=0,bR3=0,bI3=0;
    float t1c=1,t1s=0,t2c=1,t2s=0,t3c=1,t3s=0;
    float u1c=1,u1s=0,u2c=1,u2s=0,u3c=1,u3s=0;
    for (int c=0;c<128;++c){
      float xv = bf2f(xr[c]);
      h0 += xv;
      h64 += (c&1)? -xv : xv;
      aR1 += xv*t1c; aI1 += xv*t1s;
      aR2 += xv*t2c; aI2 += xv*t2s;
      aR3 += xv*t3c; aI3 += xv*t3s;
      bR1 += xv*u1c; bI1 += xv*u1s;
      bR2 += xv*u2c; bI2 += xv*u2s;
      bR3 += xv*u3c; bI3 += xv*u3s;
      float t;
      t = t1c*w1c - t1s*w1s; t1s = t1c*w1s + t1s*w1c; t1c = t;
      t = t2c*w2c - t2s*w2s; t2s = t2c*w2s + t2s*w2c; t2c = t;
      t = t3c*w3c - t3s*w3s; t3s = t3c*w3s + t3s*w3c; t3c = t;
      t = u1c*v1c - u1s*v1s; u1s = u1c*v1s + u1s*v1c; u1c = t;
      t = u2c*v2c - u2s*v2s; u2s = u2c*v2s + u2s*v2c; u2c = t;
      t = u3c*v3c - u3s*v3s; u3s = u3c*v3s + u3s*v3c; u3c = t;
    }
    Hlo[0][0][r]=h0;  Hlo[0][1][r]=0.f;
    Hlo[1][0][r]=aR1; Hlo[1][1][r]=aI1;
    Hlo[2][0][r]=aR2; Hlo[2][1][r]=aI2;
    Hlo[3][0][r]=aR3; Hlo[3][1][r]=aI3;
    Hhi[0][0][r]=bR1; Hhi[0][1][r]=bI1;
    Hhi[1][0][r]=bR2; Hhi[1][1][r]=bI2;
    Hhi[2][0][r]=bR3; Hhi[2][1][r]=bI3;
    Hhi[3][0][r]=h64; Hhi[3][1][r]=0.f;
  } else {
    // column DFT: G_w[c] = sum_r x e^{-2pi i w r/128}, w in {61..64}
    const int c = tid - 128;
    float g64=0.f;
    float bR1=0,bI1=0,bR2=0,bI2=0,bR3=0,bI3=0;
    float u1c=1,u1s=0,u2c=1,u2s=0,u3c=1,u3s=0;
    for (int r=0;r<128;++r){
      float xv = bf2f(xs[r*132 + c]);
      g64 += (r&1)? -xv : xv;
      bR1 += xv*u1c; bI1 += xv*u1s;
      bR2 += xv*u2c; bI2 += xv*u2s;
      bR3 += xv*u3c; bI3 += xv*u3s;
      float t;
      t = u1c*v1c - u1s*v1s; u1s = u1c*v1s + u1s*v1c; u1c = t;
      t = u2c*v2c - u2s*v2s; u2s = u2c*v2s + u2s*v2c; u2c = t;
      t = u3c*v3c - u3s*v3s; u3s = u3c*v3s + u3s*v3c; u3c = t;
    }
    Gg[0][0][c]=bR1; Gg[0][1][c]=bI1;
    Gg[1][0][c]=bR2; Gg[1][1][c]=bI2;
    Gg[2][0][c]=bR3; Gg[2][1][c]=bI3;
    Gg[3][0][c]=g64; Gg[3][1][c]=0.f;
  }
  __syncthreads();

  // write G, Hh sections (expand w=65,66 via conjugate symmetry), scaled 1/sqrt(128)
  #pragma unroll
  for (int k=0;k<6;++k){
    int idx = k*256 + tid;            // [0,1536)
    int w = idx >> 8, reim = (idx >> 7) & 1, c = idx & 127;
    float sg = reim ? -1.f : 1.f;
    float vG, vH;
    if (w < 4){ vG = Gg[w][reim][c];  vH = Hhi[w][reim][c]; }
    else if (w == 4){ vG = sg*Gg[2][reim][c]; vH = sg*Hhi[2][reim][c]; }
    else { vG = sg*Gg[1][reim][c]; vH = sg*Hhi[1][reim][c]; }
    ghb[idx]        = vG * INV_SQRT128;
    ghb[1536 + idx] = vH * INV_SQRT128;
  }
  // Fc[w6][z6]
  if (tid < 36){
    int wi = tid/6, zi = tid%6;
    int z = 61 + zi;
    float fR=0.f, fI=0.f;
    for (int c=0;c<128;++c){
      float gR, gI;
      if (wi < 4){ gR = Gg[wi][0][c]; gI = Gg[wi][1][c]; }
      else if (wi == 4){ gR = Gg[2][0][c]; gI = -Gg[2][1][c]; }
      else { gR = Gg[1][0][c]; gI = -Gg[1][1][c]; }
      int m = (z*c) & 127;
      float tc = twc[m], ts = tws[m];
      fR += gR*tc + gI*ts;
      fI += gI*tc - gR*ts;
    }
    ghb[3072 + tid*2]     = fR * INV128;
    ghb[3072 + tid*2 + 1] = fI * INV128;
  }
  // magC (49): |F[u,v]|, u,v in [-3,3]
  if (tid >= 64 && tid < 113){
    int i = tid - 64;
    int u = i/7 - 3, v = i%7 - 3;
    int va = v < 0 ? -v : v;
    float vsg = v < 0 ? -1.f : 1.f;
    float fR=0.f, fI=0.f;
    for (int r=0;r<128;++r){
      float hR = Hlo[va][0][r], hI = vsg*Hlo[va][1][r];
      int m = ((u*r) % 128 + 128) & 127;
      float tc = twc[m], ts = tws[m];
      fR += hR*tc + hI*ts;
      fI += hI*tc - hR*ts;
    }
    fR *= INV128; fI *= INV128;
    ghb[3144 + i] = sqrtf(fR*fR + fI*fI);
  }
}

// =====================================================================
// K_mlp: per batch: mean magC -> MLP -> anisotropic 7x7 kernel
// =====================================================================
__global__ void __launch_bounds__(64) K_mlp(const float* __restrict__ GH,
                                            const float* __restrict__ w1,
                                            const float* __restrict__ b1,
                                            const float* __restrict__ w2,
                                            const float* __restrict__ b2,
                                            float* __restrict__ kern){
  __shared__ float flat[49];
  __shared__ float hh[32];
  const int b = blockIdx.x, tid = threadIdx.x;
  if (tid < 49){
    float s = 0.f;
    for (int c=0; c<256; ++c)
      s += GH[(size_t)(b*256 + c)*GH_STRIDE + 3144 + tid];
    flat[tid] = s * (1.0f/256.0f);
  }
  __syncthreads();
  if (tid < 32){
    float s = b1[tid];
    for (int i=0; i<49; ++i) s += flat[i]*w1[tid*49+i];
    hh[tid] = fmaxf(s, 0.f);
  }
  __syncthreads();
  if (tid == 0){
    float p[3];
    #pragma unroll
    for (int k=0; k<3; ++k){
      float s = b2[k];
      for (int j=0; j<32; ++j) s += hh[j]*w2[k*32+j];
      p[k] = s;
    }
    float theta = atan2f(p[0], p[1])*0.5f + 1.57079632679489662f;
    float ct = cosf(theta), st = sinf(theta);
    float l1 = expf(p[2]);
    float l2 = 1.0f/(l1 + 1e-8f);
    float inv1 = 1.0f/(2.0f*l1*l1);
    float inv2 = 1.0f/(2.0f*l2*l2);
    float sum = 0.f;
    for (int i=0; i<7; ++i) for (int j=0; j<7; ++j){
      float yy = (float)(i-3), xx = (float)(j-3);
      float xr =  xx*ct + yy*st;
      float yr = -xx*st + yy*ct;
      sum += expf(-(xr*xr*inv1 + yr*yr*inv2));
    }
    float inv = 1.0f/(sum + 1e-8f);
    for (int i=0; i<7; ++i) for (int j=0; j<7; ++j){
      float yy = (float)(i-3), xx = (float)(j-3);
      float xr =  xx*ct + yy*st;
      float yr = -xx*st + yy*ct;
      kern[b*49 + i*7 + j] = expf(-(xr*xr*inv1 + yr*yr*inv2)) * inv;
    }
  }
}

// =====================================================================
// K3: per batch: kappa[7][2][128], lambda[7][2][128], W field [16384]
// =====================================================================
__global__ void __launch_bounds__(256) K3(const float* __restrict__ kern,
                                          float* __restrict__ KL,
                                          float* __restrict__ W){
  __shared__ float twc[128], tws[128], kl[49];
  __shared__ float kapl[7][2][128];
  const int b = blockIdx.x, tid = threadIdx.x;
  if (tid < 128){
    float s,c; __sincosf((float)tid*C128, &s, &c);
    twc[tid]=c; tws[tid]=s;
  }
  if (tid < 49) kl[tid] = kern[b*49 + tid];
  __syncthreads();
  if (tid < 128){
    const int c = tid;
    float* klb = KL + (size_t)b*3584;
    #pragma unroll
    for (int dp=0; dp<7; ++dp){
      float kR=0.f, kI=0.f;
      #pragma unroll
      for (int dq=0; dq<7; ++dq){
        int m = (((dq-3)*c) % 128 + 128) & 127;
        float kv = kl[dp*7+dq];
        kR += kv*twc[m]; kI -= kv*tws[m];
      }
      klb[(dp*2  )*128 + c] = kR;
      klb[(dp*2+1)*128 + c] = kI;
      kapl[dp][0][c] = kR; kapl[dp][1][c] = kI;
    }
    const int r = tid;
    #pragma unroll
    for (int dq=0; dq<7; ++dq){
      float lR=0.f, lI=0.f;
      #pragma unroll
      for (int dp=0; dp<7; ++dp){
        int m = (((dp-3)*r) % 128 + 128) & 127;
        float kv = kl[dp*7+dq];
        lR += kv*twc[m]; lI -= kv*tws[m];
      }
      klb[1792 + (dq*2  )*128 + r] = lR;
      klb[1792 + (dq*2+1)*128 + r] = lI;
    }
  }
  __syncthreads();
  for (int k=0;k<64;++k){
    int px = k*256 + tid;
    int r = px >> 7, c = px & 127;
    float w = 0.f;
    #pragma unroll
    for (int dp=0; dp<7; ++dp){
      int m = (((dp-3)*r) % 128 + 128) & 127;
      w += twc[m]*kapl[dp][0][c] + tws[m]*kapl[dp][1][c];
    }
    W[(size_t)b*IMG + px] = w;
  }
}

// =====================================================================
// K_tab: per image: Abar (corner-folded) and Bbar tables
// =====================================================================
__global__ void __launch_bounds__(128) K_tab(const float* __restrict__ GH,
                                             const float* __restrict__ KL,
                                             const float* __restrict__ kern,
                                             float* __restrict__ AB){
  __shared__ float dRe[36], dIm[36], kl[49];
  const int tid = threadIdx.x;
  const int img = blockIdx.x, b = img >> 8;
  const float* ghb = GH + (size_t)img*GH_STRIDE;
  const float* klb = KL + (size_t)b*3584;
  float* abb = AB + (size_t)img*AB_STRIDE;

  if (tid < 49) kl[tid] = kern[b*49 + tid];
  __syncthreads();
  if (tid < 36){
    int si = tid/6, ti = tid%6;
    float dR=0.f, dI=0.f;
    for (int j=0; j<c_pcnt[si]; ++j){
      int dp = c_pdp0[si] + j;
      int wi = (si-3) + dp;
      for (int l=0; l<c_pcnt[ti]; ++l){
        int dq = c_pdp0[ti] + l;
        int zi = (ti-3) + dq;
        float kv = kl[dp*7+dq];
        dR += kv * ghb[3072 + (wi*6+zi)*2];
        dI += kv * ghb[3072 + (wi*6+zi)*2 + 1];
      }
    }
    dRe[tid] = dR; dIm[tid] = dI;
  }
  __syncthreads();

  const int c = tid;
  // phases e^{2pi i t c/128}, t = ti-3
  float s1,c1; __sincosf((float)c*C128, &s1, &c1);
  float c2 = c1*c1 - s1*s1, s2 = 2.f*c1*s1;
  float c3 = c1*c2 - s1*s2, s3 = s1*c2 + c1*s2;
  float ct[6] = {c3,c2,c1,1.f,c1,c2};
  float st[6] = {-s3,-s2,-s1,0.f,s1,s2};
  float sgnc = (c & 1) ? -1.f : 1.f;

  float gr[6], gi[6], kr[7], ki[7];
  #pragma unroll
  for (int w=0;w<6;++w){ gr[w]=ghb[(w*2)*128+c]; gi[w]=ghb[(w*2+1)*128+c]; }
  #pragma unroll
  for (int dp=0;dp<7;++dp){ kr[dp]=klb[(dp*2)*128+c]; ki[dp]=klb[(dp*2+1)*128+c]; }

  #pragma unroll
  for (int si=0; si<6; ++si){
    float dR=0.f, dI=0.f;
    for (int j=0; j<c_pcnt[si]; ++j){
      int dp = c_pdp0[si] + j;
      int w = (si-3) + dp;
      dR += kr[dp]*gr[w] - ki[dp]*gi[w];
      dI += kr[dp]*gi[w] + ki[dp]*gr[w];
    }
    float corrR=0.f, corrI=0.f;
    #pragma unroll
    for (int ti=0; ti<6; ++ti){
      float DR = dRe[si*6+ti], DI = dIm[si*6+ti];
      corrR += DR*ct[ti] - DI*st[ti];
      corrI += DR*st[ti] + DI*ct[ti];
    }
    abb[(si*2  )*128 + c] = INV_SQRT128*dR - INV128*sgnc*corrR;
    abb[(si*2+1)*128 + c] = INV_SQRT128*dI - INV128*sgnc*corrI;
  }

  // Bbar: r = tid
  const int r = tid;
  float hr[6], hi_[6], lr[7], li[7];
  #pragma unroll
  for (int z=0;z<6;++z){ hr[z]=ghb[1536+(z*2)*128+r]; hi_[z]=ghb[1536+(z*2+1)*128+r]; }
  #pragma unroll
  for (int dq=0;dq<7;++dq){ lr[dq]=klb[1792+(dq*2)*128+r]; li[dq]=klb[1792+(dq*2+1)*128+r]; }
  #pragma unroll
  for (int ti=0; ti<6; ++ti){
    float bR=0.f, bI=0.f;
    for (int l=0; l<c_pcnt[ti]; ++l){
      int dq = c_pdp0[ti] + l;
      int z = (ti-3) + dq;
      bR += lr[dq]*hr[z] - li[dq]*hi_[z];
      bI += lr[dq]*hi_[z] + li[dq]*hr[z];
    }
    abb[1536 + r*12 + ti*2]     = INV_SQRT128*bR;
    abb[1536 + r*12 + ti*2 + 1] = INV_SQRT128*bI;
  }
}

// =====================================================================
// K4: per image: filt = x*W - E  (bf16 out)
// =====================================================================
__global__ void __launch_bounds__(256) K4(const float* __restrict__ xlow,
                                          const float* __restrict__ W,
                                          const float* __restrict__ AB,
                                          unsigned short* __restrict__ filt){
  const int tid = threadIdx.x;
  const int img = blockIdx.x, b = img >> 8;
  const int c = tid & 127, grp = tid >> 7;
  const float* abb = AB + (size_t)img*AB_STRIDE;
  const float* xim = xlow + (size_t)img*IMG;
  const float* Wb  = W + (size_t)b*IMG;
  unsigned short* fim = filt + (size_t)img*IMG;

  // hoisted per-c state
  float ar[6], ai[6];
  #pragma unroll
  for (int si=0;si<6;++si){ ar[si]=abb[(si*2)*128+c]; ai[si]=abb[(si*2+1)*128+c]; }
  float s1,c1; __sincosf((float)c*C128, &s1, &c1);
  float c2 = c1*c1 - s1*s1, s2 = 2.f*c1*s1;
  float c3 = c1*c2 - s1*s2, s3 = s1*c2 + c1*s2;
  float ctc[6] = {c3,c2,c1,1.f,c1,c2};
  float stc[6] = {-s3,-s2,-s1,0.f,s1,s2};
  const float sgnc = (c & 1) ? -1.f : 1.f;

  for (int k=0;k<64;++k){
    int ru = __builtin_amdgcn_readfirstlane(grp*64 + k);
    const float* brow = abb + 1536 + ru*12;
    float4 b0 = *(const float4*)(brow);
    float4 b1 = *(const float4*)(brow+4);
    float4 b2 = *(const float4*)(brow+8);
    float rs1,rc1; __sincosf((float)ru*C128, &rs1, &rc1);
    float rc2 = rc1*rc1 - rs1*rs1, rs2 = 2.f*rc1*rs1;
    float rc3 = rc1*rc2 - rs1*rs2, rs3 = rs1*rc2 + rc1*rs2;
    float rcs[6] = {rc3,rc2,rc1,1.f,rc1,rc2};
    float rss[6] = {-rs3,-rs2,-rs1,0.f,rs1,rs2};

    float ER = 0.f;
    #pragma unroll
    for (int si=0;si<6;++si) ER += rcs[si]*ar[si] - rss[si]*ai[si];
    ER = (ru & 1) ? -ER : ER;

    float EC = ctc[0]*b0.x - stc[0]*b0.y
             + ctc[1]*b0.z - stc[1]*b0.w
             + ctc[2]*b1.x - stc[2]*b1.y
             + ctc[3]*b1.z - stc[3]*b1.w
             + ctc[4]*b2.x - stc[4]*b2.y
             + ctc[5]*b2.z - stc[5]*b2.w;
    EC *= sgnc;

    int px = ru*128 + c;
    float val = xim[px]*Wb[px] - ER - EC;
    fim[px] = f2bf(val);
  }
}

// =====================================================================
// K_w: refine_w f32 -> bf16
// =====================================================================
__global__ void __launch_bounds__(256) K_w(const float* __restrict__ rw,
                                           unsigned short* __restrict__ rwbf){
  int i = blockIdx.x*256 + threadIdx.x;
  rwbf[i] = f2bf(rw[i]);
}

// =====================================================================
// K_trans: filt [b][c][p] bf16 -> filtT [b][p][c] bf16
// =====================================================================
__global__ void __launch_bounds__(256) K_trans(const unsigned short* __restrict__ in,
                                               unsigned short* __restrict__ outT){
  __shared__ unsigned short tile[32][33];
  const int p0 = blockIdx.x * 32;
  const int c0 = blockIdx.y * 32;
  const int b  = blockIdx.z;
  const int tx = threadIdx.x & 31, ty = threadIdx.x >> 5;
  #pragma unroll
  for (int w=0; w<4; ++w){
    int ii = ty + w*8;
    tile[ii][tx] = in[((size_t)b*NC + c0 + ii)*IMG + p0 + tx];
  }
  __syncthreads();
  #pragma unroll
  for (int w=0; w<4; ++w){
    int ii = ty + w*8;
    outT[((size_t)b*IMG + p0 + ii)*NC + c0 + tx] = tile[tx][ii];
  }
}

// =====================================================================
// K_gemm: out[b,o,p] = sum_c rw[o,c]*filt[b,c,p] + bilinear(x_high)
// =====================================================================
__global__ void __launch_bounds__(256) K_gemm(const unsigned short* __restrict__ rwbf,
                                              const unsigned short* __restrict__ filtT,
                                              const float* __restrict__ xhigh,
                                              float* __restrict__ out){
  __shared__ unsigned short At[128*32];
  __shared__ unsigned short Bt[128*32];
  const int tid = threadIdx.x, lane = tid & 63, wv = tid >> 6;
  const int wr = wv >> 1, wc = wv & 1;
  const int pt = blockIdx.x, ot = blockIdx.y, b = blockIdx.z;
  const int p0 = pt*128, o0 = ot*128;

  f32x4 acc[4][4];
  #pragma unroll
  for (int m=0;m<4;++m)
    #pragma unroll
    for (int n=0;n<4;++n){ f32x4 z = {0.f,0.f,0.f,0.f}; acc[m][n] = z; }

  const int row  = tid >> 2;
  const int koff = (tid & 3) * 8;

  for (int ks=0; ks<8; ++ks){
    const int k0 = ks*32;
    i32x4 av0 = *(const i32x4*)(&rwbf[(size_t)(o0+row   )*256 + k0 + koff]);
    i32x4 av1 = *(const i32x4*)(&rwbf[(size_t)(o0+row+64)*256 + k0 + koff]);
    i32x4 bv0 = *(const i32x4*)(&filtT[((size_t)b*IMG + p0+row   )*256 + k0 + koff]);
    i32x4 bv1 = *(const i32x4*)(&filtT[((size_t)b*IMG + p0+row+64)*256 + k0 + koff]);
    __syncthreads();
    *(i32x4*)(&At[ row     *32 + koff]) = av0;
    *(i32x4*)(&At[(row+64) *32 + koff]) = av1;
    *(i32x4*)(&Bt[ row     *32 + koff]) = bv0;
    *(i32x4*)(&Bt[(row+64) *32 + koff]) = bv1;
    __syncthreads();

    const int g = lane >> 4, r16 = lane & 15;
    bf16x8 af[4], bfr[4];
    #pragma unroll
    for (int m=0;m<4;++m) af[m]  = *(const bf16x8*)(&At[(wr*64 + m*16 + r16)*32 + g*8]);
    #pragma unroll
    for (int n=0;n<4;++n) bfr[n] = *(const bf16x8*)(&Bt[(wc*64 + n*16 + r16)*32 + g*8]);
    #pragma unroll
    for (int m=0;m<4;++m)
      #pragma unroll
      for (int n=0;n<4;++n)
        acc[m][n] = __builtin_amdgcn_mfma_f32_16x16x32_bf16(af[m], bfr[n], acc[m][n], 0, 0, 0);
  }

  const int y = pt;
  float fy = 0.5f*(float)y - 0.25f;
  int iyf = (int)floorf(fy);
  float ty = fy - (float)iyf;
  int iy0 = iyf < 0 ? 0 : iyf;
  int iy1 = (iyf+1) > 63 ? 63 : (iyf+1);
  float wy1 = ty, wy0 = 1.0f - ty;

  const int g = lane >> 4, r16 = lane & 15;
  #pragma unroll
  for (int n=0;n<4;++n){
    int xcol = wc*64 + n*16 + r16;
    float fx = 0.5f*(float)xcol - 0.25f;
    int ixf = (int)floorf(fx);
    float tx = fx - (float)ixf;
    int ix0 = ixf < 0 ? 0 : ixf;
    int ix1 = (ixf+1) > 63 ? 63 : (ixf+1);
    float wx1 = tx, wx0 = 1.0f - tx;
    #pragma unroll
    for (int m=0;m<4;++m){
      #pragma unroll
      for (int j=0;j<4;++j){
        int o = o0 + wr*64 + m*16 + g*4 + j;
        const float* xh = &xhigh[((size_t)b*NC + o)*64*64];
        float up = wy0*(wx0*xh[iy0*64+ix0] + wx1*xh[iy0*64+ix1])
                 + wy1*(wx0*xh[iy1*64+ix0] + wx1*xh[iy1*64+ix1]);
        out[((size_t)b*NC + o)*IMG + (size_t)y*NW + xcol] = acc[m][n][j] + up;
      }
    }
  }
}

// =====================================================================
extern "C" void kernel_launch(void* const* d_in, const int* in_sizes, int n_in,
                              void* d_out, int out_size, void* d_ws, size_t ws_size,
                              hipStream_t stream){
  (void)in_sizes; (void)n_in; (void)out_size; (void)ws_size;
  const float* xhigh = (const float*)d_in[0];
  const float* xlow  = (const float*)d_in[1];
  const float* w1    = (const float*)d_in[2];
  const float* b1    = (const float*)d_in[3];
  const float* w2    = (const float*)d_in[4];
  const float* b2    = (const float*)d_in[5];
  const float* rw    = (const float*)d_in[6];

  char* ws = (char*)d_ws;
  unsigned short* filt  = (unsigned short*)(ws);                    // 67,108,864
  unsigned short* filtT = (unsigned short*)(ws + 67108864);         // 67,108,864
  float* GH   = (float*)(ws + 134217728);                           // 26,214,400
  float* AB   = (float*)(ws + 160432128);                           // 25,165,824
  float* kern = (float*)(ws + 185597952);                           // 4,096 (pad)
  float* KL   = (float*)(ws + 185602048);                           // 114,688
  float* Wf   = (float*)(ws + 185716736);                           // 524,288
  unsigned short* rwbf = (unsigned short*)(ws + 186241024);         // 131,072

  K1   <<<NIMG, 256, 0, stream>>>(xlow, GH);
  K_mlp<<<NB,   64,  0, stream>>>(GH, w1, b1, w2, b2, kern);
  K3   <<<NB,   256, 0, stream>>>(kern, KL, Wf);
  K_w  <<<256,  256, 0, stream>>>(rw, rwbf);
  K_tab<<<NIMG, 128, 0, stream>>>(GH, KL, kern, AB);
  K4   <<<NIMG, 256, 0, stream>>>(xlow, Wf, AB, filt);
  K_trans<<<dim3(512, 8, NB), 256, 0, stream>>>(filt, filtT);
  K_gemm <<<dim3(128, 2, NB), 256, 0, stream>>>(rwbf, filtT, xhigh, (float*)d_out);
}

// Round 3
// 356.447 us; speedup vs baseline: 6.6273x; 1.3297x over previous
//
#include <hip/hip_runtime.h>

typedef __attribute__((ext_vector_type(8))) short bf16x8;
typedef __attribute__((ext_vector_type(4))) float f32x4;
typedef __attribute__((ext_vector_type(4))) int   i32x4;

#define PI_F 3.14159265358979323846f
#define C128 0.0490873852123405f      /* 2*pi/128 */
#define INV_SQRT128 0.0883883476483184f
#define INV128 0.0078125f

#define NB 8
#define NC 256
#define NH 128
#define NW 128
#define IMG 16384
#define NIMG 2048

// GH per-image layout (floats, stride 3200):
//  [0..1535]    G  : [w6][re/im][128]   (w = 61..66)
//  [1536..3071] Hh : [z6][re/im][128]   (z = 61..66)
//  [3072..3143] Fc : 36 complex (w6 x z6)
//  [3144..3192] magC: 49
#define GH_STRIDE 3200
// AB per-image layout (floats, stride 3072):
//  [0..1535]    Abar planes [si*2+reim][128]
//  [1536..3071] Bbar rows   [r][ti*2+reim] (12 per row)
#define AB_STRIDE 3072

__device__ __forceinline__ unsigned short f2bf(float f){
  unsigned int u = __float_as_uint(f);
  u += 0x7FFFu + ((u >> 16) & 1u);
  return (unsigned short)(u >> 16);
}
__device__ __forceinline__ float bf2f(unsigned short u){
  return __uint_as_float(((unsigned int)u) << 16);
}

// wrap-pair tables: si=0..5 <-> s=si-3; dp in [pdp0, pdp0+pcnt)
__device__ __constant__ int c_pcnt[6] = {1,2,3,3,2,1};
__device__ __constant__ int c_pdp0[6] = {6,5,4,0,0,0};

// =====================================================================
// K1: per image: high-freq partial DFTs G,Hh + corner Fc + magC(49)
// =====================================================================
__global__ void __launch_bounds__(256) K1(const float* __restrict__ xlow,
                                          float* __restrict__ GH){
  __shared__ unsigned short xs[128*132];
  __shared__ float Hlo[4][2][128];   // z=0..3
  __shared__ float Hhi[4][2][128];   // z=61,62,63,64
  __shared__ float Gg [4][2][128];   // w=61,62,63,64
  __shared__ float twc[128], tws[128];

  const int tid = threadIdx.x;
  const int img = blockIdx.x;
  float* ghb = GH + (size_t)img*GH_STRIDE;

  if (tid < 128){
    float s,c; __sincosf((float)tid*C128, &s, &c);
    twc[tid]=c; tws[tid]=s;
  }
  {
    const float4* xp = (const float4*)(xlow + (size_t)img*IMG);
    #pragma unroll
    for (int k=0; k<16; ++k){
      int e4 = k*256 + tid;
      float4 v = xp[e4];
      int px = e4*4;
      int r = px >> 7, c = px & 127;
      ushort4 u; u.x=f2bf(v.x); u.y=f2bf(v.y); u.z=f2bf(v.z); u.w=f2bf(v.w);
      *(ushort4*)(&xs[r*132 + c]) = u;
    }
  }
  __syncthreads();

  const float w1c= 0.9987954562051724f, w1s=-0.0490676743274180f;
  const float w2c= 0.9951847266721969f, w2s=-0.0980171403295606f;
  const float w3c= 0.9891765099647810f, w3s=-0.1467304744553617f;
  const float v1c=-0.9891765099647810f, v1s=-0.1467304744553617f;
  const float v2c=-0.9951847266721969f, v2s=-0.0980171403295606f;
  const float v3c=-0.9987954562051724f, v3s=-0.0490676743274180f;

  if (tid < 128){
    const int r = tid;
    const unsigned short* xr = &xs[r*132];
    float h0=0.f, h64=0.f;
    float aR1=0,aI1=0,aR2=0,aI2=0,aR3=0,aI3=0;
    float bR1=0,bI1=0,bR2=0,bI2=0,bR3=0,bI3=0;
    float t1c=1,t1s=0,t2c=1,t2s=0,t3c=1,t3s=0;
    float u1c=1,u1s=0,u2c=1,u2s=0,u3c=1,u3s=0;
    for (int c=0;c<128;++c){
      float xv = bf2f(xr[c]);
      h0 += xv;
      h64 += (c&1)? -xv : xv;
      aR1 += xv*t1c; aI1 += xv*t1s;
      aR2 += xv*t2c; aI2 += xv*t2s;
      aR3 += xv*t3c; aI3 += xv*t3s;
      bR1 += xv*u1c; bI1 += xv*u1s;
      bR2 += xv*u2c; bI2 += xv*u2s;
      bR3 += xv*u3c; bI3 += xv*u3s;
      float t;
      t = t1c*w1c - t1s*w1s; t1s = t1c*w1s + t1s*w1c; t1c = t;
      t = t2c*w2c - t2s*w2s; t2s = t2c*w2s + t2s*w2c; t2c = t;
      t = t3c*w3c - t3s*w3s; t3s = t3c*w3s + t3s*w3c; t3c = t;
      t = u1c*v1c - u1s*v1s; u1s = u1c*v1s + u1s*v1c; u1c = t;
      t = u2c*v2c - u2s*v2s; u2s = u2c*v2s + u2s*v2c; u2c = t;
      t = u3c*v3c - u3s*v3s; u3s = u3c*v3s + u3s*v3c; u3c = t;
    }
    Hlo[0][0][r]=h0;  Hlo[0][1][r]=0.f;
    Hlo[1][0][r]=aR1; Hlo[1][1][r]=aI1;
    Hlo[2][0][r]=aR2; Hlo[2][1][r]=aI2;
    Hlo[3][0][r]=aR3; Hlo[3][1][r]=aI3;
    Hhi[0][0][r]=bR1; Hhi[0][1][r]=bI1;
    Hhi[1][0][r]=bR2; Hhi[1][1][r]=bI2;
    Hhi[2][0][r]=bR3; Hhi[2][1][r]=bI3;
    Hhi[3][0][r]=h64; Hhi[3][1][r]=0.f;
  } else {
    const int c = tid - 128;
    float g64=0.f;
    float bR1=0,bI1=0,bR2=0,bI2=0,bR3=0,bI3=0;
    float u1c=1,u1s=0,u2c=1,u2s=0,u3c=1,u3s=0;
    for (int r=0;r<128;++r){
      float xv = bf2f(xs[r*132 + c]);
      g64 += (r&1)? -xv : xv;
      bR1 += xv*u1c; bI1 += xv*u1s;
      bR2 += xv*u2c; bI2 += xv*u2s;
      bR3 += xv*u3c; bI3 += xv*u3s;
      float t;
      t = u1c*v1c - u1s*v1s; u1s = u1c*v1s + u1s*v1c; u1c = t;
      t = u2c*v2c - u2s*v2s; u2s = u2c*v2s + u2s*v2c; u2c = t;
      t = u3c*v3c - u3s*v3s; u3s = u3c*v3s + u3s*v3c; u3c = t;
    }
    Gg[0][0][c]=bR1; Gg[0][1][c]=bI1;
    Gg[1][0][c]=bR2; Gg[1][1][c]=bI2;
    Gg[2][0][c]=bR3; Gg[2][1][c]=bI3;
    Gg[3][0][c]=g64; Gg[3][1][c]=0.f;
  }
  __syncthreads();

  #pragma unroll
  for (int k=0;k<6;++k){
    int idx = k*256 + tid;
    int w = idx >> 8, reim = (idx >> 7) & 1, c = idx & 127;
    float sg = reim ? -1.f : 1.f;
    float vG, vH;
    if (w < 4){ vG = Gg[w][reim][c];  vH = Hhi[w][reim][c]; }
    else if (w == 4){ vG = sg*Gg[2][reim][c]; vH = sg*Hhi[2][reim][c]; }
    else { vG = sg*Gg[1][reim][c]; vH = sg*Hhi[1][reim][c]; }
    ghb[idx]        = vG * INV_SQRT128;
    ghb[1536 + idx] = vH * INV_SQRT128;
  }
  if (tid < 36){
    int wi = tid/6, zi = tid%6;
    int z = 61 + zi;
    float fR=0.f, fI=0.f;
    for (int c=0;c<128;++c){
      float gR, gI;
      if (wi < 4){ gR = Gg[wi][0][c]; gI = Gg[wi][1][c]; }
      else if (wi == 4){ gR = Gg[2][0][c]; gI = -Gg[2][1][c]; }
      else { gR = Gg[1][0][c]; gI = -Gg[1][1][c]; }
      int m = (z*c) & 127;
      float tc = twc[m], ts = tws[m];
      fR += gR*tc + gI*ts;
      fI += gI*tc - gR*ts;
    }
    ghb[3072 + tid*2]     = fR * INV128;
    ghb[3072 + tid*2 + 1] = fI * INV128;
  }
  if (tid >= 64 && tid < 113){
    int i = tid - 64;
    int u = i/7 - 3, v = i%7 - 3;
    int va = v < 0 ? -v : v;
    float vsg = v < 0 ? -1.f : 1.f;
    float fR=0.f, fI=0.f;
    for (int r=0;r<128;++r){
      float hR = Hlo[va][0][r], hI = vsg*Hlo[va][1][r];
      int m = ((u*r) % 128 + 128) & 127;
      float tc = twc[m], ts = tws[m];
      fR += hR*tc + hI*ts;
      fI += hI*tc - hR*ts;
    }
    fR *= INV128; fI *= INV128;
    ghb[3144 + i] = sqrtf(fR*fR + fI*fI);
  }
}

// =====================================================================
// K_mlp
// =====================================================================
__global__ void __launch_bounds__(64) K_mlp(const float* __restrict__ GH,
                                            const float* __restrict__ w1,
                                            const float* __restrict__ b1,
                                            const float* __restrict__ w2,
                                            const float* __restrict__ b2,
                                            float* __restrict__ kern){
  __shared__ float flat[49];
  __shared__ float hh[32];
  const int b = blockIdx.x, tid = threadIdx.x;
  if (tid < 49){
    float s = 0.f;
    for (int c=0; c<256; ++c)
      s += GH[(size_t)(b*256 + c)*GH_STRIDE + 3144 + tid];
    flat[tid] = s * (1.0f/256.0f);
  }
  __syncthreads();
  if (tid < 32){
    float s = b1[tid];
    for (int i=0; i<49; ++i) s += flat[i]*w1[tid*49+i];
    hh[tid] = fmaxf(s, 0.f);
  }
  __syncthreads();
  if (tid == 0){
    float p[3];
    #pragma unroll
    for (int k=0; k<3; ++k){
      float s = b2[k];
      for (int j=0; j<32; ++j) s += hh[j]*w2[k*32+j];
      p[k] = s;
    }
    float theta = atan2f(p[0], p[1])*0.5f + 1.57079632679489662f;
    float ct = cosf(theta), st = sinf(theta);
    float l1 = expf(p[2]);
    float l2 = 1.0f/(l1 + 1e-8f);
    float inv1 = 1.0f/(2.0f*l1*l1);
    float inv2 = 1.0f/(2.0f*l2*l2);
    float sum = 0.f;
    for (int i=0; i<7; ++i) for (int j=0; j<7; ++j){
      float yy = (float)(i-3), xx = (float)(j-3);
      float xr =  xx*ct + yy*st;
      float yr = -xx*st + yy*ct;
      sum += expf(-(xr*xr*inv1 + yr*yr*inv2));
    }
    float inv = 1.0f/(sum + 1e-8f);
    for (int i=0; i<7; ++i) for (int j=0; j<7; ++j){
      float yy = (float)(i-3), xx = (float)(j-3);
      float xr =  xx*ct + yy*st;
      float yr = -xx*st + yy*ct;
      kern[b*49 + i*7 + j] = expf(-(xr*xr*inv1 + yr*yr*inv2)) * inv;
    }
  }
}

// =====================================================================
// K3: per batch: kappa/lambda tables + W field
// =====================================================================
__global__ void __launch_bounds__(256) K3(const float* __restrict__ kern,
                                          float* __restrict__ KL,
                                          float* __restrict__ W){
  __shared__ float twc[128], tws[128], kl[49];
  __shared__ float kapl[7][2][128];
  const int b = blockIdx.x, tid = threadIdx.x;
  if (tid < 128){
    float s,c; __sincosf((float)tid*C128, &s, &c);
    twc[tid]=c; tws[tid]=s;
  }
  if (tid < 49) kl[tid] = kern[b*49 + tid];
  __syncthreads();
  if (tid < 128){
    const int c = tid;
    float* klb = KL + (size_t)b*3584;
    #pragma unroll
    for (int dp=0; dp<7; ++dp){
      float kR=0.f, kI=0.f;
      #pragma unroll
      for (int dq=0; dq<7; ++dq){
        int m = (((dq-3)*c) % 128 + 128) & 127;
        float kv = kl[dp*7+dq];
        kR += kv*twc[m]; kI -= kv*tws[m];
      }
      klb[(dp*2  )*128 + c] = kR;
      klb[(dp*2+1)*128 + c] = kI;
      kapl[dp][0][c] = kR; kapl[dp][1][c] = kI;
    }
    const int r = tid;
    #pragma unroll
    for (int dq=0; dq<7; ++dq){
      float lR=0.f, lI=0.f;
      #pragma unroll
      for (int dp=0; dp<7; ++dp){
        int m = (((dp-3)*r) % 128 + 128) & 127;
        float kv = kl[dp*7+dq];
        lR += kv*twc[m]; lI -= kv*tws[m];
      }
      klb[1792 + (dq*2  )*128 + r] = lR;
      klb[1792 + (dq*2+1)*128 + r] = lI;
    }
  }
  __syncthreads();
  for (int k=0;k<64;++k){
    int px = k*256 + tid;
    int r = px >> 7, c = px & 127;
    float w = 0.f;
    #pragma unroll
    for (int dp=0; dp<7; ++dp){
      int m = (((dp-3)*r) % 128 + 128) & 127;
      w += twc[m]*kapl[dp][0][c] + tws[m]*kapl[dp][1][c];
    }
    W[(size_t)b*IMG + px] = w;
  }
}

// =====================================================================
// K_tab: per image: Abar (corner-folded) and Bbar tables
// =====================================================================
__global__ void __launch_bounds__(128) K_tab(const float* __restrict__ GH,
                                             const float* __restrict__ KL,
                                             const float* __restrict__ kern,
                                             float* __restrict__ AB){
  __shared__ float dRe[36], dIm[36], kl[49];
  const int tid = threadIdx.x;
  const int img = blockIdx.x, b = img >> 8;
  const float* ghb = GH + (size_t)img*GH_STRIDE;
  const float* klb = KL + (size_t)b*3584;
  float* abb = AB + (size_t)img*AB_STRIDE;

  if (tid < 49) kl[tid] = kern[b*49 + tid];
  __syncthreads();
  if (tid < 36){
    int si = tid/6, ti = tid%6;
    float dR=0.f, dI=0.f;
    for (int j=0; j<c_pcnt[si]; ++j){
      int dp = c_pdp0[si] + j;
      int wi = (si-3) + dp;
      for (int l=0; l<c_pcnt[ti]; ++l){
        int dq = c_pdp0[ti] + l;
        int zi = (ti-3) + dq;
        float kv = kl[dp*7+dq];
        dR += kv * ghb[3072 + (wi*6+zi)*2];
        dI += kv * ghb[3072 + (wi*6+zi)*2 + 1];
      }
    }
    dRe[tid] = dR; dIm[tid] = dI;
  }
  __syncthreads();

  const int c = tid;
  float s1,c1; __sincosf((float)c*C128, &s1, &c1);
  float c2 = c1*c1 - s1*s1, s2 = 2.f*c1*s1;
  float c3 = c1*c2 - s1*s2, s3 = s1*c2 + c1*s2;
  float ct[6] = {c3,c2,c1,1.f,c1,c2};
  float st[6] = {-s3,-s2,-s1,0.f,s1,s2};
  float sgnc = (c & 1) ? -1.f : 1.f;

  float gr[6], gi[6], kr[7], ki[7];
  #pragma unroll
  for (int w=0;w<6;++w){ gr[w]=ghb[(w*2)*128+c]; gi[w]=ghb[(w*2+1)*128+c]; }
  #pragma unroll
  for (int dp=0;dp<7;++dp){ kr[dp]=klb[(dp*2)*128+c]; ki[dp]=klb[(dp*2+1)*128+c]; }

  #pragma unroll
  for (int si=0; si<6; ++si){
    float dR=0.f, dI=0.f;
    for (int j=0; j<c_pcnt[si]; ++j){
      int dp = c_pdp0[si] + j;
      int w = (si-3) + dp;
      dR += kr[dp]*gr[w] - ki[dp]*gi[w];
      dI += kr[dp]*gi[w] + ki[dp]*gr[w];
    }
    float corrR=0.f, corrI=0.f;
    #pragma unroll
    for (int ti=0; ti<6; ++ti){
      float DR = dRe[si*6+ti], DI = dIm[si*6+ti];
      corrR += DR*ct[ti] - DI*st[ti];
      corrI += DR*st[ti] + DI*ct[ti];
    }
    abb[(si*2  )*128 + c] = INV_SQRT128*dR - INV128*sgnc*corrR;
    abb[(si*2+1)*128 + c] = INV_SQRT128*dI - INV128*sgnc*corrI;
  }

  const int r = tid;
  float hr[6], hi_[6], lr[7], li[7];
  #pragma unroll
  for (int z=0;z<6;++z){ hr[z]=ghb[1536+(z*2)*128+r]; hi_[z]=ghb[1536+(z*2+1)*128+r]; }
  #pragma unroll
  for (int dq=0;dq<7;++dq){ lr[dq]=klb[1792+(dq*2)*128+r]; li[dq]=klb[1792+(dq*2+1)*128+r]; }
  #pragma unroll
  for (int ti=0; ti<6; ++ti){
    float bR=0.f, bI=0.f;
    for (int l=0; l<c_pcnt[ti]; ++l){
      int dq = c_pdp0[ti] + l;
      int z = (ti-3) + dq;
      bR += lr[dq]*hr[z] - li[dq]*hi_[z];
      bI += lr[dq]*hi_[z] + li[dq]*hr[z];
    }
    abb[1536 + r*12 + ti*2]     = INV_SQRT128*bR;
    abb[1536 + r*12 + ti*2 + 1] = INV_SQRT128*bI;
  }
}

// =====================================================================
// K4: per image: filt = x*W - E  (bf16 out), float2 per lane
// =====================================================================
__global__ void __launch_bounds__(256) K4(const float* __restrict__ xlow,
                                          const float* __restrict__ W,
                                          const float* __restrict__ AB,
                                          unsigned short* __restrict__ filt){
  const int tid = threadIdx.x;
  const int img = blockIdx.x, b = img >> 8;
  const int c0 = (tid & 63)*2, grp = tid >> 6;
  const float* abb = AB + (size_t)img*AB_STRIDE;
  const float* xim = xlow + (size_t)img*IMG;
  const float* Wb  = W + (size_t)b*IMG;
  unsigned short* fim = filt + (size_t)img*IMG;

  float ar[2][6], ai[2][6], ctc[2][6], stc[2][6];
  #pragma unroll
  for (int col=0; col<2; ++col){
    int c = c0 + col;
    #pragma unroll
    for (int si=0;si<6;++si){ ar[col][si]=abb[(si*2)*128+c]; ai[col][si]=abb[(si*2+1)*128+c]; }
    float s1,c1; __sincosf((float)c*C128, &s1, &c1);
    float c2 = c1*c1 - s1*s1, s2 = 2.f*c1*s1;
    float c3 = c1*c2 - s1*s2, s3 = s1*c2 + c1*s2;
    ctc[col][0]=c3; ctc[col][1]=c2; ctc[col][2]=c1; ctc[col][3]=1.f; ctc[col][4]=c1; ctc[col][5]=c2;
    stc[col][0]=-s3; stc[col][1]=-s2; stc[col][2]=-s1; stc[col][3]=0.f; stc[col][4]=s1; stc[col][5]=s2;
  }

  for (int k=0;k<32;++k){
    int ru = __builtin_amdgcn_readfirstlane(grp*32 + k);
    const float* brow = abb + 1536 + ru*12;
    float4 b0 = *(const float4*)(brow);
    float4 b1 = *(const float4*)(brow+4);
    float4 b2 = *(const float4*)(brow+8);
    float rs1,rc1; __sincosf((float)ru*C128, &rs1, &rc1);
    float rc2 = rc1*rc1 - rs1*rs1, rs2 = 2.f*rc1*rs1;
    float rc3 = rc1*rc2 - rs1*rs2, rs3 = rs1*rc2 + rc1*rs2;
    float rcs[6] = {rc3,rc2,rc1,1.f,rc1,rc2};
    float rss[6] = {-rs3,-rs2,-rs1,0.f,rs1,rs2};

    float ER0 = 0.f, ER1 = 0.f;
    #pragma unroll
    for (int si=0;si<6;++si){
      ER0 += rcs[si]*ar[0][si] - rss[si]*ai[0][si];
      ER1 += rcs[si]*ar[1][si] - rss[si]*ai[1][si];
    }
    float rsg = (ru & 1) ? -1.f : 1.f;
    ER0 *= rsg; ER1 *= rsg;

    float bRv[6] = {b0.x, b0.z, b1.x, b1.z, b2.x, b2.z};
    float bIv[6] = {b0.y, b0.w, b1.y, b1.w, b2.y, b2.w};
    float EC0 = 0.f, EC1 = 0.f;
    #pragma unroll
    for (int ti=0;ti<6;++ti){
      EC0 += ctc[0][ti]*bRv[ti] - stc[0][ti]*bIv[ti];
      EC1 += ctc[1][ti]*bRv[ti] - stc[1][ti]*bIv[ti];
    }
    // c0 even -> +EC0 ; c0+1 odd -> -EC1
    int px = ru*128 + c0;
    float2 xv = *(const float2*)(&xim[px]);
    float2 wv = *(const float2*)(&Wb[px]);
    float v0 = xv.x*wv.x - ER0 - EC0;
    float v1 = xv.y*wv.y - ER1 + EC1;
    unsigned int pack = ((unsigned int)f2bf(v1) << 16) | (unsigned int)f2bf(v0);
    *(unsigned int*)(&fim[px]) = pack;
  }
}

// =====================================================================
// K_w: refine_w f32 -> bf16
// =====================================================================
__global__ void __launch_bounds__(256) K_w(const float* __restrict__ rw,
                                           unsigned short* __restrict__ rwbf){
  int i = blockIdx.x*256 + threadIdx.x;
  rwbf[i] = f2bf(rw[i]);
}

// =====================================================================
// K_up: bilinear upsample x_high (64x64 -> 128x128) as bf16
// =====================================================================
__global__ void __launch_bounds__(256) K_up(const float* __restrict__ xhigh,
                                            unsigned short* __restrict__ up){
  __shared__ float xs[64*68];
  const int tid = threadIdx.x;
  const int img = blockIdx.x;
  const float* src = xhigh + (size_t)img*4096;
  unsigned short* dst = up + (size_t)img*IMG;

  #pragma unroll
  for (int p=0; p<4; ++p){
    int t = p*256 + tid;           // float4 index, 1024 total
    float4 v = ((const float4*)src)[t];
    int r = t >> 4, k = t & 15;
    *(float4*)(&xs[r*68 + k*4]) = v;
  }
  __syncthreads();

  for (int k=0; k<32; ++k){
    int pr = k*256 + tid;          // output PAIR index (8192 pairs)
    int y = pr >> 6, x0 = (pr & 63)*2;
    float fy = 0.5f*(float)y - 0.25f;
    int iyf = (int)floorf(fy);
    float ty = fy - (float)iyf;
    int iy0 = iyf < 0 ? 0 : iyf;
    int iy1 = (iyf+1) > 63 ? 63 : (iyf+1);
    float wy1 = ty, wy0 = 1.0f - ty;
    const float* r0 = &xs[iy0*68];
    const float* r1 = &xs[iy1*68];

    float outv[2];
    #pragma unroll
    for (int e=0; e<2; ++e){
      int x = x0 + e;
      float fx = 0.5f*(float)x - 0.25f;
      int ixf = (int)floorf(fx);
      float tx = fx - (float)ixf;
      int ix0 = ixf < 0 ? 0 : ixf;
      int ix1 = (ixf+1) > 63 ? 63 : (ixf+1);
      float wx1 = tx, wx0 = 1.0f - tx;
      outv[e] = wy0*(wx0*r0[ix0] + wx1*r0[ix1])
              + wy1*(wx0*r1[ix0] + wx1*r1[ix1]);
    }
    unsigned int pack = ((unsigned int)f2bf(outv[1]) << 16) | (unsigned int)f2bf(outv[0]);
    *(unsigned int*)(&dst[y*NW + x0]) = pack;
  }
}

// =====================================================================
// K_trans: filt [b][c][p] bf16 -> filtT [b][p][c] bf16
// =====================================================================
__global__ void __launch_bounds__(256) K_trans(const unsigned short* __restrict__ in,
                                               unsigned short* __restrict__ outT){
  __shared__ unsigned short tile[32][33];
  const int p0 = blockIdx.x * 32;
  const int c0 = blockIdx.y * 32;
  const int b  = blockIdx.z;
  const int tx = threadIdx.x & 31, ty = threadIdx.x >> 5;
  #pragma unroll
  for (int w=0; w<4; ++w){
    int ii = ty + w*8;
    tile[ii][tx] = in[((size_t)b*NC + c0 + ii)*IMG + p0 + tx];
  }
  __syncthreads();
  #pragma unroll
  for (int w=0; w<4; ++w){
    int ii = ty + w*8;
    outT[((size_t)b*IMG + p0 + ii)*NC + c0 + tx] = tile[tx][ii];
  }
}

// =====================================================================
// K_gemm: out[b,o,p] = sum_c rw[o,c]*filt[b,c,p] + up[b,o,p]
// XCD-paired grid: the two o-tiles of one p-tile are 8 block-ids apart
// so they land on the same XCD (round-robin) and share filtT in L2.
// =====================================================================
__global__ void __launch_bounds__(256) K_gemm(const unsigned short* __restrict__ rwbf,
                                              const unsigned short* __restrict__ filtT,
                                              const unsigned short* __restrict__ up,
                                              float* __restrict__ out){
  __shared__ unsigned short At[128*32];
  __shared__ unsigned short Bt[128*32];
  const int tid = threadIdx.x, lane = tid & 63, wv = tid >> 6;
  const int wr = wv >> 1, wc = wv & 1;
  const int xg = blockIdx.x;                 // 0..255
  const int g16 = xg >> 4, i16 = xg & 15;
  const int ot = i16 >> 3, pt = (g16 << 3) | (i16 & 7);
  const int b = blockIdx.z;
  const int p0 = pt*128, o0 = ot*128;

  f32x4 acc[4][4];
  #pragma unroll
  for (int m=0;m<4;++m)
    #pragma unroll
    for (int n=0;n<4;++n){ f32x4 z = {0.f,0.f,0.f,0.f}; acc[m][n] = z; }

  const int row  = tid >> 2;
  const int koff = (tid & 3) * 8;

  for (int ks=0; ks<8; ++ks){
    const int k0 = ks*32;
    i32x4 av0 = *(const i32x4*)(&rwbf[(size_t)(o0+row   )*256 + k0 + koff]);
    i32x4 av1 = *(const i32x4*)(&rwbf[(size_t)(o0+row+64)*256 + k0 + koff]);
    i32x4 bv0 = *(const i32x4*)(&filtT[((size_t)b*IMG + p0+row   )*256 + k0 + koff]);
    i32x4 bv1 = *(const i32x4*)(&filtT[((size_t)b*IMG + p0+row+64)*256 + k0 + koff]);
    __syncthreads();
    *(i32x4*)(&At[ row     *32 + koff]) = av0;
    *(i32x4*)(&At[(row+64) *32 + koff]) = av1;
    *(i32x4*)(&Bt[ row     *32 + koff]) = bv0;
    *(i32x4*)(&Bt[(row+64) *32 + koff]) = bv1;
    __syncthreads();

    const int g = lane >> 4, r16 = lane & 15;
    bf16x8 af[4], bfr[4];
    #pragma unroll
    for (int m=0;m<4;++m) af[m]  = *(const bf16x8*)(&At[(wr*64 + m*16 + r16)*32 + g*8]);
    #pragma unroll
    for (int n=0;n<4;++n) bfr[n] = *(const bf16x8*)(&Bt[(wc*64 + n*16 + r16)*32 + g*8]);
    #pragma unroll
    for (int m=0;m<4;++m)
      #pragma unroll
      for (int n=0;n<4;++n)
        acc[m][n] = __builtin_amdgcn_mfma_f32_16x16x32_bf16(af[m], bfr[n], acc[m][n], 0, 0, 0);
  }

  // epilogue: out = acc + up (same address load/store, coalesced)
  const int y = pt;
  const int g = lane >> 4, r16 = lane & 15;
  #pragma unroll
  for (int m=0;m<4;++m){
    #pragma unroll
    for (int j=0;j<4;++j){
      int o = o0 + wr*64 + m*16 + g*4 + j;
      size_t base = (size_t)(b*NC + o)*IMG + (size_t)y*NW;
      #pragma unroll
      for (int n=0;n<4;++n){
        int xcol = wc*64 + n*16 + r16;
        float upv = bf2f(up[base + xcol]);
        out[base + xcol] = acc[m][n][j] + upv;
      }
    }
  }
}

// =====================================================================
extern "C" void kernel_launch(void* const* d_in, const int* in_sizes, int n_in,
                              void* d_out, int out_size, void* d_ws, size_t ws_size,
                              hipStream_t stream){
  (void)in_sizes; (void)n_in; (void)out_size; (void)ws_size;
  const float* xhigh = (const float*)d_in[0];
  const float* xlow  = (const float*)d_in[1];
  const float* w1    = (const float*)d_in[2];
  const float* b1    = (const float*)d_in[3];
  const float* w2    = (const float*)d_in[4];
  const float* b2    = (const float*)d_in[5];
  const float* rw    = (const float*)d_in[6];

  char* ws = (char*)d_ws;
  unsigned short* filt  = (unsigned short*)(ws);                    // 67,108,864
  unsigned short* filtT = (unsigned short*)(ws + 67108864);         // 67,108,864
  float* GH   = (float*)(ws + 134217728);                           // 26,214,400
  float* AB   = (float*)(ws + 160432128);                           // 25,165,824
  float* kern = (float*)(ws + 185597952);                           // 4,096 (pad)
  float* KL   = (float*)(ws + 185602048);                           // 114,688
  float* Wf   = (float*)(ws + 185716736);                           // 524,288
  unsigned short* rwbf = (unsigned short*)(ws + 186241024);         // 131,072
  unsigned short* up   = filt;   // reuse: filt is dead after K_trans

  K1   <<<NIMG, 256, 0, stream>>>(xlow, GH);
  K_mlp<<<NB,   64,  0, stream>>>(GH, w1, b1, w2, b2, kern);
  K3   <<<NB,   256, 0, stream>>>(kern, KL, Wf);
  K_w  <<<256,  256, 0, stream>>>(rw, rwbf);
  K_tab<<<NIMG, 128, 0, stream>>>(GH, KL, kern, AB);
  K4   <<<NIMG, 256, 0, stream>>>(xlow, Wf, AB, filt);
  K_trans<<<dim3(512, 8, NB), 256, 0, stream>>>(filt, filtT);
  K_up <<<NIMG, 256, 0, stream>>>(xhigh, up);
  K_gemm <<<dim3(256, 1, NB), 256, 0, stream>>>(rwbf, filtT, up, (float*)d_out);
}

// Round 4
// 314.109 us; speedup vs baseline: 7.5206x; 1.1348x over previous
//
#include <hip/hip_runtime.h>

typedef __attribute__((ext_vector_type(8))) short bf16x8;
typedef __attribute__((ext_vector_type(4))) float f32x4;
typedef __attribute__((ext_vector_type(4))) int   i32x4;

#define PI_F 3.14159265358979323846f
#define C128 0.0490873852123405f      /* 2*pi/128 */
#define INV_SQRT128 0.0883883476483184f
#define INV128 0.0078125f

#define NB 8
#define NC 256
#define NH 128
#define NW 128
#define IMG 16384
#define NIMG 2048
#define XST 130                      /* xs LDS stride in u16 (dword-stride 65, odd) */

// GH per-image layout (floats, stride 3200):
//  [0..1535]    G  : [w6][re/im][128]   (w = 61..66)
//  [1536..3071] Hh : [z6][re/im][128]   (z = 61..66)
//  [3072..3143] Fc : 36 complex (w6 x z6)
//  [3144..3192] magC: 49
#define GH_STRIDE 3200
// AB per-image layout (floats, stride 3072)
#define AB_STRIDE 3072

__device__ __forceinline__ unsigned short f2bf(float f){
  unsigned int u = __float_as_uint(f);
  u += 0x7FFFu + ((u >> 16) & 1u);
  return (unsigned short)(u >> 16);
}
__device__ __forceinline__ float bf2f(unsigned short u){
  return __uint_as_float(((unsigned int)u) << 16);
}

__device__ __constant__ int c_pcnt[6] = {1,2,3,3,2,1};
__device__ __constant__ int c_pdp0[6] = {6,5,4,0,0,0};

#define COS1 0.9987954562051724f
#define SIN1 0.0490676743274180f
#define K1CH (2.0f*COS1)

// =====================================================================
// K1: per image: high-freq partial DFTs G,Hh + corner Fc + magC(49)
// Parity-split accumulators + Chebyshev twiddles.
// =====================================================================
__global__ void __launch_bounds__(256) K1(const float* __restrict__ xlow,
                                          float* __restrict__ GH){
  __shared__ unsigned short xs[128*XST];
  __shared__ float Hlo[4][2][128];   // z=0..3
  __shared__ float Hhi[4][2][128];   // z=61,62,63,64
  __shared__ float Gg [4][2][128];   // w=61,62,63,64
  __shared__ float twc[128], tws[128];

  const int tid = threadIdx.x;
  const int img = blockIdx.x;
  float* ghb = GH + (size_t)img*GH_STRIDE;

  if (tid < 128){
    float s,c; __sincosf((float)tid*C128, &s, &c);
    twc[tid]=c; tws[tid]=s;
  }
  {
    const float4* xp = (const float4*)(xlow + (size_t)img*IMG);
    #pragma unroll
    for (int k=0; k<16; ++k){
      int e4 = k*256 + tid;
      float4 v = xp[e4];
      int px = e4*4;
      int r = px >> 7, c = px & 127;
      unsigned int pw0 = (unsigned int)f2bf(v.x) | ((unsigned int)f2bf(v.y) << 16);
      unsigned int pw1 = (unsigned int)f2bf(v.z) | ((unsigned int)f2bf(v.w) << 16);
      *(unsigned int*)(&xs[r*XST + c    ]) = pw0;
      *(unsigned int*)(&xs[r*XST + c + 2]) = pw1;
    }
  }
  __syncthreads();

  float A0e=0.f, A0o=0.f;
  float Ce1=0.f,Se1=0.f,Co1=0.f,So1=0.f;
  float Ce2=0.f,Se2=0.f,Co2=0.f,So2=0.f;
  float Ce3=0.f,Se3=0.f,Co3=0.f,So3=0.f;

  if (tid < 128){
    // -------- row DFT over c (parity split) --------
    const int r = tid;
    const unsigned short* xr = &xs[r*XST];
    float cp = 1.f, sp = 0.f;        // angle at even pos
    float cn = COS1, sn = SIN1;      // angle at odd pos
    #pragma unroll 4
    for (int j=0; j<64; ++j){
      unsigned int pk = *(const unsigned int*)(&xr[2*j]);
      float xe = __uint_as_float(pk << 16);
      float xo = __uint_as_float(pk & 0xffff0000u);
      // even
      {
        float t2 = cp + cp;
        float c2 = fmaf(t2, cp, -1.f);
        float s2 = t2 * sp;
        float c3 = fmaf(t2, c2, -cp);
        float s3 = fmaf(t2, s2, -sp);
        A0e += xe;
        Ce1 = fmaf(xe, cp, Ce1); Se1 = fmaf(xe, sp, Se1);
        Ce2 = fmaf(xe, c2, Ce2); Se2 = fmaf(xe, s2, Se2);
        Ce3 = fmaf(xe, c3, Ce3); Se3 = fmaf(xe, s3, Se3);
      }
      // odd
      {
        float t2 = cn + cn;
        float c2 = fmaf(t2, cn, -1.f);
        float s2 = t2 * sn;
        float c3 = fmaf(t2, c2, -cn);
        float s3 = fmaf(t2, s2, -sn);
        A0o += xo;
        Co1 = fmaf(xo, cn, Co1); So1 = fmaf(xo, sn, So1);
        Co2 = fmaf(xo, c2, Co2); So2 = fmaf(xo, s2, So2);
        Co3 = fmaf(xo, c3, Co3); So3 = fmaf(xo, s3, So3);
      }
      // advance both chains by 2 (Chebyshev 3-term)
      float cpn = fmaf(K1CH, cn, -cp);
      float spn = fmaf(K1CH, sn, -sp);
      float cnn = fmaf(K1CH, cpn, -cn);
      float snn = fmaf(K1CH, spn, -sn);
      cp = cpn; sp = spn; cn = cnn; sn = snn;
    }
    Hlo[0][0][r]=A0e+A0o;  Hlo[0][1][r]=0.f;
    Hlo[1][0][r]=Ce1+Co1;  Hlo[1][1][r]=-(Se1+So1);
    Hlo[2][0][r]=Ce2+Co2;  Hlo[2][1][r]=-(Se2+So2);
    Hlo[3][0][r]=Ce3+Co3;  Hlo[3][1][r]=-(Se3+So3);
    Hhi[0][0][r]=Ce3-Co3;  Hhi[0][1][r]=Se3-So3;   // z=61
    Hhi[1][0][r]=Ce2-Co2;  Hhi[1][1][r]=Se2-So2;   // z=62
    Hhi[2][0][r]=Ce1-Co1;  Hhi[2][1][r]=Se1-So1;   // z=63
    Hhi[3][0][r]=A0e-A0o;  Hhi[3][1][r]=0.f;       // z=64
  } else {
    // -------- column DFT over r (parity split) --------
    const int c = tid - 128;
    float cp = 1.f, sp = 0.f;
    float cn = COS1, sn = SIN1;
    #pragma unroll 4
    for (int j=0; j<64; ++j){
      float xe = bf2f(xs[(2*j  )*XST + c]);
      float xo = bf2f(xs[(2*j+1)*XST + c]);
      {
        float t2 = cp + cp;
        float c2 = fmaf(t2, cp, -1.f);
        float s2 = t2 * sp;
        float c3 = fmaf(t2, c2, -cp);
        float s3 = fmaf(t2, s2, -sp);
        A0e += xe;
        Ce1 = fmaf(xe, cp, Ce1); Se1 = fmaf(xe, sp, Se1);
        Ce2 = fmaf(xe, c2, Ce2); Se2 = fmaf(xe, s2, Se2);
        Ce3 = fmaf(xe, c3, Ce3); Se3 = fmaf(xe, s3, Se3);
      }
      {
        float t2 = cn + cn;
        float c2 = fmaf(t2, cn, -1.f);
        float s2 = t2 * sn;
        float c3 = fmaf(t2, c2, -cn);
        float s3 = fmaf(t2, s2, -sn);
        A0o += xo;
        Co1 = fmaf(xo, cn, Co1); So1 = fmaf(xo, sn, So1);
        Co2 = fmaf(xo, c2, Co2); So2 = fmaf(xo, s2, So2);
        Co3 = fmaf(xo, c3, Co3); So3 = fmaf(xo, s3, So3);
      }
      float cpn = fmaf(K1CH, cn, -cp);
      float spn = fmaf(K1CH, sn, -sp);
      float cnn = fmaf(K1CH, cpn, -cn);
      float snn = fmaf(K1CH, spn, -sn);
      cp = cpn; sp = spn; cn = cnn; sn = snn;
    }
    Gg[0][0][c]=Ce3-Co3;  Gg[0][1][c]=Se3-So3;     // w=61
    Gg[1][0][c]=Ce2-Co2;  Gg[1][1][c]=Se2-So2;     // w=62
    Gg[2][0][c]=Ce1-Co1;  Gg[2][1][c]=Se1-So1;     // w=63
    Gg[3][0][c]=A0e-A0o;  Gg[3][1][c]=0.f;         // w=64
  }
  __syncthreads();

  #pragma unroll
  for (int k=0;k<6;++k){
    int idx = k*256 + tid;
    int w = idx >> 8, reim = (idx >> 7) & 1, c = idx & 127;
    float sg = reim ? -1.f : 1.f;
    float vG, vH;
    if (w < 4){ vG = Gg[w][reim][c];  vH = Hhi[w][reim][c]; }
    else if (w == 4){ vG = sg*Gg[2][reim][c]; vH = sg*Hhi[2][reim][c]; }
    else { vG = sg*Gg[1][reim][c]; vH = sg*Hhi[1][reim][c]; }
    ghb[idx]        = vG * INV_SQRT128;
    ghb[1536 + idx] = vH * INV_SQRT128;
  }
  if (tid < 36){
    int wi = tid/6, zi = tid%6;
    int z = 61 + zi;
    float fR=0.f, fI=0.f;
    for (int c=0;c<128;++c){
      float gR, gI;
      if (wi < 4){ gR = Gg[wi][0][c]; gI = Gg[wi][1][c]; }
      else if (wi == 4){ gR = Gg[2][0][c]; gI = -Gg[2][1][c]; }
      else { gR = Gg[1][0][c]; gI = -Gg[1][1][c]; }
      int m = (z*c) & 127;
      float tc = twc[m], ts = tws[m];
      fR += gR*tc + gI*ts;
      fI += gI*tc - gR*ts;
    }
    ghb[3072 + tid*2]     = fR * INV128;
    ghb[3072 + tid*2 + 1] = fI * INV128;
  }
  if (tid >= 64 && tid < 113){
    int i = tid - 64;
    int u = i/7 - 3, v = i%7 - 3;
    int va = v < 0 ? -v : v;
    float vsg = v < 0 ? -1.f : 1.f;
    float fR=0.f, fI=0.f;
    for (int r=0;r<128;++r){
      float hR = Hlo[va][0][r], hI = vsg*Hlo[va][1][r];
      int m = ((u*r) % 128 + 128) & 127;
      float tc = twc[m], ts = tws[m];
      fR += hR*tc + hI*ts;
      fI += hI*tc - hR*ts;
    }
    fR *= INV128; fI *= INV128;
    ghb[3144 + i] = sqrtf(fR*fR + fI*fI);
  }
}

// =====================================================================
// K_mlp
// =====================================================================
__global__ void __launch_bounds__(64) K_mlp(const float* __restrict__ GH,
                                            const float* __restrict__ w1,
                                            const float* __restrict__ b1,
                                            const float* __restrict__ w2,
                                            const float* __restrict__ b2,
                                            float* __restrict__ kern){
  __shared__ float flat[49];
  __shared__ float hh[32];
  const int b = blockIdx.x, tid = threadIdx.x;
  if (tid < 49){
    float s = 0.f;
    for (int c=0; c<256; ++c)
      s += GH[(size_t)(b*256 + c)*GH_STRIDE + 3144 + tid];
    flat[tid] = s * (1.0f/256.0f);
  }
  __syncthreads();
  if (tid < 32){
    float s = b1[tid];
    for (int i=0; i<49; ++i) s += flat[i]*w1[tid*49+i];
    hh[tid] = fmaxf(s, 0.f);
  }
  __syncthreads();
  if (tid == 0){
    float p[3];
    #pragma unroll
    for (int k=0; k<3; ++k){
      float s = b2[k];
      for (int j=0; j<32; ++j) s += hh[j]*w2[k*32+j];
      p[k] = s;
    }
    float theta = atan2f(p[0], p[1])*0.5f + 1.57079632679489662f;
    float ct = cosf(theta), st = sinf(theta);
    float l1 = expf(p[2]);
    float l2 = 1.0f/(l1 + 1e-8f);
    float inv1 = 1.0f/(2.0f*l1*l1);
    float inv2 = 1.0f/(2.0f*l2*l2);
    float sum = 0.f;
    for (int i=0; i<7; ++i) for (int j=0; j<7; ++j){
      float yy = (float)(i-3), xx = (float)(j-3);
      float xr =  xx*ct + yy*st;
      float yr = -xx*st + yy*ct;
      sum += expf(-(xr*xr*inv1 + yr*yr*inv2));
    }
    float inv = 1.0f/(sum + 1e-8f);
    for (int i=0; i<7; ++i) for (int j=0; j<7; ++j){
      float yy = (float)(i-3), xx = (float)(j-3);
      float xr =  xx*ct + yy*st;
      float yr = -xx*st + yy*ct;
      kern[b*49 + i*7 + j] = expf(-(xr*xr*inv1 + yr*yr*inv2)) * inv;
    }
  }
}

// =====================================================================
// K3: per batch: kappa/lambda tables + W field
// =====================================================================
__global__ void __launch_bounds__(256) K3(const float* __restrict__ kern,
                                          float* __restrict__ KL,
                                          float* __restrict__ W){
  __shared__ float twc[128], tws[128], kl[49];
  __shared__ float kapl[7][2][128];
  const int b = blockIdx.x, tid = threadIdx.x;
  if (tid < 128){
    float s,c; __sincosf((float)tid*C128, &s, &c);
    twc[tid]=c; tws[tid]=s;
  }
  if (tid < 49) kl[tid] = kern[b*49 + tid];
  __syncthreads();
  if (tid < 128){
    const int c = tid;
    float* klb = KL + (size_t)b*3584;
    #pragma unroll
    for (int dp=0; dp<7; ++dp){
      float kR=0.f, kI=0.f;
      #pragma unroll
      for (int dq=0; dq<7; ++dq){
        int m = (((dq-3)*c) % 128 + 128) & 127;
        float kv = kl[dp*7+dq];
        kR += kv*twc[m]; kI -= kv*tws[m];
      }
      klb[(dp*2  )*128 + c] = kR;
      klb[(dp*2+1)*128 + c] = kI;
      kapl[dp][0][c] = kR; kapl[dp][1][c] = kI;
    }
    const int r = tid;
    #pragma unroll
    for (int dq=0; dq<7; ++dq){
      float lR=0.f, lI=0.f;
      #pragma unroll
      for (int dp=0; dp<7; ++dp){
        int m = (((dp-3)*r) % 128 + 128) & 127;
        float kv = kl[dp*7+dq];
        lR += kv*twc[m]; lI -= kv*tws[m];
      }
      klb[1792 + (dq*2  )*128 + r] = lR;
      klb[1792 + (dq*2+1)*128 + r] = lI;
    }
  }
  __syncthreads();
  for (int k=0;k<64;++k){
    int px = k*256 + tid;
    int r = px >> 7, c = px & 127;
    float w = 0.f;
    #pragma unroll
    for (int dp=0; dp<7; ++dp){
      int m = (((dp-3)*r) % 128 + 128) & 127;
      w += twc[m]*kapl[dp][0][c] + tws[m]*kapl[dp][1][c];
    }
    W[(size_t)b*IMG + px] = w;
  }
}

// =====================================================================
// K_tab: per image: Abar (corner-folded) and Bbar tables
// =====================================================================
__global__ void __launch_bounds__(128) K_tab(const float* __restrict__ GH,
                                             const float* __restrict__ KL,
                                             const float* __restrict__ kern,
                                             float* __restrict__ AB){
  __shared__ float dRe[36], dIm[36], kl[49];
  const int tid = threadIdx.x;
  const int img = blockIdx.x, b = img >> 8;
  const float* ghb = GH + (size_t)img*GH_STRIDE;
  const float* klb = KL + (size_t)b*3584;
  float* abb = AB + (size_t)img*AB_STRIDE;

  if (tid < 49) kl[tid] = kern[b*49 + tid];
  __syncthreads();
  if (tid < 36){
    int si = tid/6, ti = tid%6;
    float dR=0.f, dI=0.f;
    for (int j=0; j<c_pcnt[si]; ++j){
      int dp = c_pdp0[si] + j;
      int wi = (si-3) + dp;
      for (int l=0; l<c_pcnt[ti]; ++l){
        int dq = c_pdp0[ti] + l;
        int zi = (ti-3) + dq;
        float kv = kl[dp*7+dq];
        dR += kv * ghb[3072 + (wi*6+zi)*2];
        dI += kv * ghb[3072 + (wi*6+zi)*2 + 1];
      }
    }
    dRe[tid] = dR; dIm[tid] = dI;
  }
  __syncthreads();

  const int c = tid;
  float s1,c1; __sincosf((float)c*C128, &s1, &c1);
  float c2 = c1*c1 - s1*s1, s2 = 2.f*c1*s1;
  float c3 = c1*c2 - s1*s2, s3 = s1*c2 + c1*s2;
  float ct[6] = {c3,c2,c1,1.f,c1,c2};
  float st[6] = {-s3,-s2,-s1,0.f,s1,s2};
  float sgnc = (c & 1) ? -1.f : 1.f;

  float gr[6], gi[6], kr[7], ki[7];
  #pragma unroll
  for (int w=0;w<6;++w){ gr[w]=ghb[(w*2)*128+c]; gi[w]=ghb[(w*2+1)*128+c]; }
  #pragma unroll
  for (int dp=0;dp<7;++dp){ kr[dp]=klb[(dp*2)*128+c]; ki[dp]=klb[(dp*2+1)*128+c]; }

  #pragma unroll
  for (int si=0; si<6; ++si){
    float dR=0.f, dI=0.f;
    for (int j=0; j<c_pcnt[si]; ++j){
      int dp = c_pdp0[si] + j;
      int w = (si-3) + dp;
      dR += kr[dp]*gr[w] - ki[dp]*gi[w];
      dI += kr[dp]*gi[w] + ki[dp]*gr[w];
    }
    float corrR=0.f, corrI=0.f;
    #pragma unroll
    for (int ti=0; ti<6; ++ti){
      float DR = dRe[si*6+ti], DI = dIm[si*6+ti];
      corrR += DR*ct[ti] - DI*st[ti];
      corrI += DR*st[ti] + DI*ct[ti];
    }
    abb[(si*2  )*128 + c] = INV_SQRT128*dR - INV128*sgnc*corrR;
    abb[(si*2+1)*128 + c] = INV_SQRT128*dI - INV128*sgnc*corrI;
  }

  const int r = tid;
  float hr[6], hi_[6], lr[7], li[7];
  #pragma unroll
  for (int z=0;z<6;++z){ hr[z]=ghb[1536+(z*2)*128+r]; hi_[z]=ghb[1536+(z*2+1)*128+r]; }
  #pragma unroll
  for (int dq=0;dq<7;++dq){ lr[dq]=klb[1792+(dq*2)*128+r]; li[dq]=klb[1792+(dq*2+1)*128+r]; }
  #pragma unroll
  for (int ti=0; ti<6; ++ti){
    float bR=0.f, bI=0.f;
    for (int l=0; l<c_pcnt[ti]; ++l){
      int dq = c_pdp0[ti] + l;
      int z = (ti-3) + dq;
      bR += lr[dq]*hr[z] - li[dq]*hi_[z];
      bI += lr[dq]*hi_[z] + li[dq]*hr[z];
    }
    abb[1536 + r*12 + ti*2]     = INV_SQRT128*bR;
    abb[1536 + r*12 + ti*2 + 1] = INV_SQRT128*bI;
  }
}

// =====================================================================
// K4: per image: filt = x*W - E  (bf16 out), float2 per lane
// =====================================================================
__global__ void __launch_bounds__(256) K4(const float* __restrict__ xlow,
                                          const float* __restrict__ W,
                                          const float* __restrict__ AB,
                                          unsigned short* __restrict__ filt){
  const int tid = threadIdx.x;
  const int img = blockIdx.x, b = img >> 8;
  const int c0 = (tid & 63)*2, grp = tid >> 6;
  const float* abb = AB + (size_t)img*AB_STRIDE;
  const float* xim = xlow + (size_t)img*IMG;
  const float* Wb  = W + (size_t)b*IMG;
  unsigned short* fim = filt + (size_t)img*IMG;

  float ar[2][6], ai[2][6], ctc[2][6], stc[2][6];
  #pragma unroll
  for (int col=0; col<2; ++col){
    int c = c0 + col;
    #pragma unroll
    for (int si=0;si<6;++si){ ar[col][si]=abb[(si*2)*128+c]; ai[col][si]=abb[(si*2+1)*128+c]; }
    float s1,c1; __sincosf((float)c*C128, &s1, &c1);
    float c2 = c1*c1 - s1*s1, s2 = 2.f*c1*s1;
    float c3 = c1*c2 - s1*s2, s3 = s1*c2 + c1*s2;
    ctc[col][0]=c3; ctc[col][1]=c2; ctc[col][2]=c1; ctc[col][3]=1.f; ctc[col][4]=c1; ctc[col][5]=c2;
    stc[col][0]=-s3; stc[col][1]=-s2; stc[col][2]=-s1; stc[col][3]=0.f; stc[col][4]=s1; stc[col][5]=s2;
  }

  for (int k=0;k<32;++k){
    int ru = __builtin_amdgcn_readfirstlane(grp*32 + k);
    const float* brow = abb + 1536 + ru*12;
    float4 b0 = *(const float4*)(brow);
    float4 b1 = *(const float4*)(brow+4);
    float4 b2 = *(const float4*)(brow+8);
    float rs1,rc1; __sincosf((float)ru*C128, &rs1, &rc1);
    float rc2 = rc1*rc1 - rs1*rs1, rs2 = 2.f*rc1*rs1;
    float rc3 = rc1*rc2 - rs1*rs2, rs3 = rs1*rc2 + rc1*rs2;
    float rcs[6] = {rc3,rc2,rc1,1.f,rc1,rc2};
    float rss[6] = {-rs3,-rs2,-rs1,0.f,rs1,rs2};

    float ER0 = 0.f, ER1 = 0.f;
    #pragma unroll
    for (int si=0;si<6;++si){
      ER0 += rcs[si]*ar[0][si] - rss[si]*ai[0][si];
      ER1 += rcs[si]*ar[1][si] - rss[si]*ai[1][si];
    }
    float rsg = (ru & 1) ? -1.f : 1.f;
    ER0 *= rsg; ER1 *= rsg;

    float bRv[6] = {b0.x, b0.z, b1.x, b1.z, b2.x, b2.z};
    float bIv[6] = {b0.y, b0.w, b1.y, b1.w, b2.y, b2.w};
    float EC0 = 0.f, EC1 = 0.f;
    #pragma unroll
    for (int ti=0;ti<6;++ti){
      EC0 += ctc[0][ti]*bRv[ti] - stc[0][ti]*bIv[ti];
      EC1 += ctc[1][ti]*bRv[ti] - stc[1][ti]*bIv[ti];
    }
    int px = ru*128 + c0;
    float2 xv = *(const float2*)(&xim[px]);
    float2 wv = *(const float2*)(&Wb[px]);
    float v0 = xv.x*wv.x - ER0 - EC0;
    float v1 = xv.y*wv.y - ER1 + EC1;
    unsigned int pack = ((unsigned int)f2bf(v1) << 16) | (unsigned int)f2bf(v0);
    *(unsigned int*)(&fim[px]) = pack;
  }
}

// =====================================================================
// K_w: refine_w f32 -> bf16
// =====================================================================
__global__ void __launch_bounds__(256) K_w(const float* __restrict__ rw,
                                           unsigned short* __restrict__ rwbf){
  int i = blockIdx.x*256 + threadIdx.x;
  rwbf[i] = f2bf(rw[i]);
}

// =====================================================================
// K_up: bilinear upsample x_high (64x64 -> 128x128) as bf16
// =====================================================================
__global__ void __launch_bounds__(256) K_up(const float* __restrict__ xhigh,
                                            unsigned short* __restrict__ up){
  __shared__ float xs[64*68];
  const int tid = threadIdx.x;
  const int img = blockIdx.x;
  const float* src = xhigh + (size_t)img*4096;
  unsigned short* dst = up + (size_t)img*IMG;

  #pragma unroll
  for (int p=0; p<4; ++p){
    int t = p*256 + tid;
    float4 v = ((const float4*)src)[t];
    int r = t >> 4, k = t & 15;
    *(float4*)(&xs[r*68 + k*4]) = v;
  }
  __syncthreads();

  for (int k=0; k<32; ++k){
    int pr = k*256 + tid;
    int y = pr >> 6, x0 = (pr & 63)*2;
    float fy = 0.5f*(float)y - 0.25f;
    int iyf = (int)floorf(fy);
    float ty = fy - (float)iyf;
    int iy0 = iyf < 0 ? 0 : iyf;
    int iy1 = (iyf+1) > 63 ? 63 : (iyf+1);
    float wy1 = ty, wy0 = 1.0f - ty;
    const float* r0 = &xs[iy0*68];
    const float* r1 = &xs[iy1*68];

    float outv[2];
    #pragma unroll
    for (int e=0; e<2; ++e){
      int x = x0 + e;
      float fx = 0.5f*(float)x - 0.25f;
      int ixf = (int)floorf(fx);
      float tx = fx - (float)ixf;
      int ix0 = ixf < 0 ? 0 : ixf;
      int ix1 = (ixf+1) > 63 ? 63 : (ixf+1);
      float wx1 = tx, wx0 = 1.0f - tx;
      outv[e] = wy0*(wx0*r0[ix0] + wx1*r0[ix1])
              + wy1*(wx0*r1[ix0] + wx1*r1[ix1]);
    }
    unsigned int pack = ((unsigned int)f2bf(outv[1]) << 16) | (unsigned int)f2bf(outv[0]);
    *(unsigned int*)(&dst[y*NW + x0]) = pack;
  }
}

// =====================================================================
// K_trans: filt [b][c][p] -> filtT [b][p][c], 64x64 tiles, ushort4 I/O
// =====================================================================
__global__ void __launch_bounds__(256) K_trans(const unsigned short* __restrict__ in,
                                               unsigned short* __restrict__ outT){
  __shared__ unsigned short tile[64*68];    // [p][c], stride 68
  const int p0 = blockIdx.x * 64;
  const int c0 = blockIdx.y * 64;
  const int b  = blockIdx.z;
  const int tid = threadIdx.x;
  const int lo = tid >> 4;          // 0..15
  const int q4 = (tid & 15) * 4;    // 0..60

  #pragma unroll
  for (int pass=0; pass<4; ++pass){
    int cc = lo + pass*16;
    ushort4 v = *(const ushort4*)(&in[((size_t)b*NC + c0 + cc)*IMG + p0 + q4]);
    tile[(q4+0)*68 + cc] = v.x;
    tile[(q4+1)*68 + cc] = v.y;
    tile[(q4+2)*68 + cc] = v.z;
    tile[(q4+3)*68 + cc] = v.w;
  }
  __syncthreads();
  #pragma unroll
  for (int pass=0; pass<4; ++pass){
    int pp = lo + pass*16;
    ushort4 v = *(const ushort4*)(&tile[pp*68 + q4]);
    *(ushort4*)(&outT[((size_t)b*IMG + p0 + pp)*NC + c0 + q4]) = v;
  }
}

// =====================================================================
// K_gemm: out[b,o,p] = sum_c rw[o,c]*filt[b,c,p] + up[b,o,p]
// Double-buffered LDS, 1 barrier per K-step. XCD-paired grid.
// =====================================================================
__global__ void __launch_bounds__(256) K_gemm(const unsigned short* __restrict__ rwbf,
                                              const unsigned short* __restrict__ filtT,
                                              const unsigned short* __restrict__ up,
                                              float* __restrict__ out){
  __shared__ unsigned short At[2][128*32];
  __shared__ unsigned short Bt[2][128*32];
  const int tid = threadIdx.x, lane = tid & 63, wv = tid >> 6;
  const int wr = wv >> 1, wc = wv & 1;
  const int xg = blockIdx.x;
  const int g16 = xg >> 4, i16 = xg & 15;
  const int ot = i16 >> 3, pt = (g16 << 3) | (i16 & 7);
  const int b = blockIdx.z;
  const int p0 = pt*128, o0 = ot*128;

  f32x4 acc[4][4];
  #pragma unroll
  for (int m=0;m<4;++m)
    #pragma unroll
    for (int n=0;n<4;++n){ f32x4 z = {0.f,0.f,0.f,0.f}; acc[m][n] = z; }

  const int row  = tid >> 2;
  const int koff = (tid & 3) * 8;
  const unsigned short* aP0 = &rwbf[(size_t)(o0+row   )*256 + koff];
  const unsigned short* aP1 = &rwbf[(size_t)(o0+row+64)*256 + koff];
  const unsigned short* bP0 = &filtT[((size_t)b*IMG + p0+row   )*256 + koff];
  const unsigned short* bP1 = &filtT[((size_t)b*IMG + p0+row+64)*256 + koff];

  i32x4 av0 = *(const i32x4*)(aP0);
  i32x4 av1 = *(const i32x4*)(aP1);
  i32x4 bv0 = *(const i32x4*)(bP0);
  i32x4 bv1 = *(const i32x4*)(bP1);
  *(i32x4*)(&At[0][ row     *32 + koff]) = av0;
  *(i32x4*)(&At[0][(row+64) *32 + koff]) = av1;
  *(i32x4*)(&Bt[0][ row     *32 + koff]) = bv0;
  *(i32x4*)(&Bt[0][(row+64) *32 + koff]) = bv1;
  __syncthreads();

  const int g = lane >> 4, r16 = lane & 15;
  for (int ks=0; ks<8; ++ks){
    const int cur = ks & 1;
    if (ks < 7){
      const int k0 = (ks+1)*32;
      av0 = *(const i32x4*)(aP0 + k0);
      av1 = *(const i32x4*)(aP1 + k0);
      bv0 = *(const i32x4*)(bP0 + k0);
      bv1 = *(const i32x4*)(bP1 + k0);
    }
    bf16x8 af[4], bfr[4];
    #pragma unroll
    for (int m=0;m<4;++m) af[m]  = *(const bf16x8*)(&At[cur][(wr*64 + m*16 + r16)*32 + g*8]);
    #pragma unroll
    for (int n=0;n<4;++n) bfr[n] = *(const bf16x8*)(&Bt[cur][(wc*64 + n*16 + r16)*32 + g*8]);
    #pragma unroll
    for (int m=0;m<4;++m)
      #pragma unroll
      for (int n=0;n<4;++n)
        acc[m][n] = __builtin_amdgcn_mfma_f32_16x16x32_bf16(af[m], bfr[n], acc[m][n], 0, 0, 0);
    if (ks < 7){
      const int nxt = cur ^ 1;
      *(i32x4*)(&At[nxt][ row     *32 + koff]) = av0;
      *(i32x4*)(&At[nxt][(row+64) *32 + koff]) = av1;
      *(i32x4*)(&Bt[nxt][ row     *32 + koff]) = bv0;
      *(i32x4*)(&Bt[nxt][(row+64) *32 + koff]) = bv1;
      __syncthreads();
    }
  }

  const int y = pt;
  #pragma unroll
  for (int m=0;m<4;++m){
    #pragma unroll
    for (int j=0;j<4;++j){
      int o = o0 + wr*64 + m*16 + g*4 + j;
      size_t base = (size_t)(b*NC + o)*IMG + (size_t)y*NW;
      #pragma unroll
      for (int n=0;n<4;++n){
        int xcol = wc*64 + n*16 + r16;
        float upv = bf2f(up[base + xcol]);
        out[base + xcol] = acc[m][n][j] + upv;
      }
    }
  }
}

// =====================================================================
extern "C" void kernel_launch(void* const* d_in, const int* in_sizes, int n_in,
                              void* d_out, int out_size, void* d_ws, size_t ws_size,
                              hipStream_t stream){
  (void)in_sizes; (void)n_in; (void)out_size; (void)ws_size;
  const float* xhigh = (const float*)d_in[0];
  const float* xlow  = (const float*)d_in[1];
  const float* w1    = (const float*)d_in[2];
  const float* b1    = (const float*)d_in[3];
  const float* w2    = (const float*)d_in[4];
  const float* b2    = (const float*)d_in[5];
  const float* rw    = (const float*)d_in[6];

  char* ws = (char*)d_ws;
  unsigned short* filt  = (unsigned short*)(ws);                    // 67,108,864
  unsigned short* filtT = (unsigned short*)(ws + 67108864);         // 67,108,864
  float* GH   = (float*)(ws + 134217728);                           // 26,214,400
  float* AB   = (float*)(ws + 160432128);                           // 25,165,824
  float* kern = (float*)(ws + 185597952);                           // 4,096 (pad)
  float* KL   = (float*)(ws + 185602048);                           // 114,688
  float* Wf   = (float*)(ws + 185716736);                           // 524,288
  unsigned short* rwbf = (unsigned short*)(ws + 186241024);         // 131,072
  unsigned short* up   = filt;   // reuse: filt is dead after K_trans

  K1   <<<NIMG, 256, 0, stream>>>(xlow, GH);
  K_mlp<<<NB,   64,  0, stream>>>(GH, w1, b1, w2, b2, kern);
  K3   <<<NB,   256, 0, stream>>>(kern, KL, Wf);
  K_w  <<<256,  256, 0, stream>>>(rw, rwbf);
  K_tab<<<NIMG, 128, 0, stream>>>(GH, KL, kern, AB);
  K4   <<<NIMG, 256, 0, stream>>>(xlow, Wf, AB, filt);
  K_trans<<<dim3(256, 4, NB), 256, 0, stream>>>(filt, filtT);
  K_up <<<NIMG, 256, 0, stream>>>(xhigh, up);
  K_gemm <<<dim3(256, 1, NB), 256, 0, stream>>>(rwbf, filtT, up, (float*)d_out);
}

// Round 5
// 293.677 us; speedup vs baseline: 8.0439x; 1.0696x over previous
//
#include <hip/hip_runtime.h>

typedef __attribute__((ext_vector_type(8))) short bf16x8;
typedef __attribute__((ext_vector_type(4))) float f32x4;
typedef __attribute__((ext_vector_type(4))) int   i32x4;

#define PI_F 3.14159265358979323846f
#define C128 0.0490873852123405f      /* 2*pi/128 */
#define INV_SQRT128 0.0883883476483184f
#define INV128 0.0078125f

#define NB 8
#define NC 256
#define NH 128
#define NW 128
#define IMG 16384
#define NIMG 2048

// GH per-image layout (floats, stride 3200):
//  [0..1535]    G  : [w6][re/im][128]   (w = 61..66)
//  [1536..3071] Hh : [z6][re/im][128]   (z = 61..66)
//  [3072..3143] Fc : 36 complex (w6 x z6)
//  [3144..3192] magC: 49
#define GH_STRIDE 3200
// AB per-image layout (floats, stride 3072)
#define AB_STRIDE 3072

__device__ __forceinline__ unsigned short f2bf(float f){
  unsigned int u = __float_as_uint(f);
  u += 0x7FFFu + ((u >> 16) & 1u);
  return (unsigned short)(u >> 16);
}
__device__ __forceinline__ float bf2f(unsigned short u){
  return __uint_as_float(((unsigned int)u) << 16);
}

__device__ __constant__ int c_pcnt[6] = {1,2,3,3,2,1};
__device__ __constant__ int c_pdp0[6] = {6,5,4,0,0,0};

#define COS1 0.9987954562051724f
#define SIN1 0.0490676743274180f
#define K1CH (2.0f*COS1)

// LDS float offsets for K1 (total 10240 floats = 40960 B -> 4 blocks/CU)
#define SM_GG   8320     /* Gg [4][2][128] = 1024 floats */
#define SM_HLR  9344     /* HloR [4][128]  = 512 floats  */
#define SM_HLI  9856     /* HloI [3][128]  = 384 floats  */
#define SM_SCRG 1920     /* col scratch (aliases xs)     */

// =====================================================================
// K1: per image: high-freq partial DFTs G,Hh + corner Fc + magC(49).
// 512 threads: 256 row-DFT (half-row each), 256 col-DFT (half-col each).
// Halves combine via LDS scratch aliasing the dead xs region.
// =====================================================================
__global__ void __launch_bounds__(512, 8) K1(const float* __restrict__ xlow,
                                             float* __restrict__ GH){
  __shared__ float smem[10240];
  unsigned short* xs = (unsigned short*)smem;   // stride 130 u16
  const int tid = threadIdx.x;
  const int img = blockIdx.x;
  float* ghb = GH + (size_t)img*GH_STRIDE;

  // ---- stage x -> bf16 LDS ----
  {
    const float4* xp = (const float4*)(xlow + (size_t)img*IMG);
    #pragma unroll
    for (int k=0; k<8; ++k){
      int e4 = k*512 + tid;
      float4 v = xp[e4];
      int r = e4 >> 5, c = (e4 & 31)*4;
      unsigned int pw0 = (unsigned int)f2bf(v.x) | ((unsigned int)f2bf(v.y) << 16);
      unsigned int pw1 = (unsigned int)f2bf(v.z) | ((unsigned int)f2bf(v.w) << 16);
      *(unsigned int*)(&xs[r*130 + c    ]) = pw0;
      *(unsigned int*)(&xs[r*130 + c + 2]) = pw1;
    }
  }
  __syncthreads();

  // acc: 0 A0e,1 A0o,2 Ce1,3 Se1,4 Co1,5 So1,6 Ce2,7 Se2,8 Co2,9 So2,
  //      10 Ce3,11 Se3,12 Co3,13 So3
  float acc[14];
  #pragma unroll
  for (int i=0;i<14;++i) acc[i]=0.f;

  const int isRow = (tid < 256);
  const int lid  = isRow ? tid : (tid-256);
  const int idx  = lid & 127;          // r for rows, c for cols
  const int half = lid >> 7;

  {
    const float sg0 = half ? -1.f : 1.f;
    float cp = sg0, sp = 0.f;
    float cn = sg0*COS1, sn = sg0*SIN1;

#define K1_ACCUM(xv, cc, ss)                                   \
    {                                                          \
      float t2 = cc + cc;                                      \
      float c2 = fmaf(t2, cc, -1.f);                           \
      float s2 = t2 * ss;                                      \
      float c3 = fmaf(t2, c2, -cc);                            \
      float s3 = fmaf(t2, s2, -ss);                            \
      acc[0 + PARITY] += xv;                                   \
      acc[2 + PARITY*2]  = fmaf(xv, cc, acc[2 + PARITY*2]);    \
      acc[3 + PARITY*2]  = fmaf(xv, ss, acc[3 + PARITY*2]);    \
      acc[6 + PARITY*2]  = fmaf(xv, c2, acc[6 + PARITY*2]);    \
      acc[7 + PARITY*2]  = fmaf(xv, s2, acc[7 + PARITY*2]);    \
      acc[10 + PARITY*2] = fmaf(xv, c3, acc[10 + PARITY*2]);   \
      acc[11 + PARITY*2] = fmaf(xv, s3, acc[11 + PARITY*2]);   \
    }

    if (isRow){
      const unsigned short* xr = &xs[idx*130 + half*64];
      #pragma unroll 4
      for (int j=0; j<32; ++j){
        unsigned int pk = *(const unsigned int*)(&xr[2*j]);
        float xe = __uint_as_float(pk << 16);
        float xo = __uint_as_float(pk & 0xffff0000u);
#define PARITY 0
        K1_ACCUM(xe, cp, sp)
#undef PARITY
#define PARITY 1
        K1_ACCUM(xo, cn, sn)
#undef PARITY
        float cpn = fmaf(K1CH, cn, -cp);
        float spn = fmaf(K1CH, sn, -sp);
        float cnn = fmaf(K1CH, cpn, -cn);
        float snn = fmaf(K1CH, spn, -sn);
        cp = cpn; sp = spn; cn = cnn; sn = snn;
      }
    } else {
      const unsigned short* xc = &xs[half*64*130 + idx];
      #pragma unroll 4
      for (int j=0; j<32; ++j){
        float xe = bf2f(xc[(2*j  )*130]);
        float xo = bf2f(xc[(2*j+1)*130]);
#define PARITY 0
        K1_ACCUM(xe, cp, sp)
#undef PARITY
#define PARITY 1
        K1_ACCUM(xo, cn, sn)
#undef PARITY
        float cpn = fmaf(K1CH, cn, -cp);
        float spn = fmaf(K1CH, sn, -sp);
        float cnn = fmaf(K1CH, cpn, -cn);
        float snn = fmaf(K1CH, spn, -sn);
        cp = cpn; sp = spn; cn = cnn; sn = snn;
      }
    }
#undef K1_ACCUM
  }
  __syncthreads();     // xs reads done; scratch may overwrite

  const int scrbase = (isRow ? 0 : SM_SCRG) + idx*15;
  if (half){
    #pragma unroll
    for (int i=0;i<14;++i) smem[scrbase+i] = acc[i];
  }
  __syncthreads();
  if (!half){
    #pragma unroll
    for (int i=0;i<14;++i) acc[i] += smem[scrbase+i];
    float A0e=acc[0],A0o=acc[1],Ce1=acc[2],Se1=acc[3],Co1=acc[4],So1=acc[5],
          Ce2=acc[6],Se2=acc[7],Co2=acc[8],So2=acc[9],
          Ce3=acc[10],Se3=acc[11],Co3=acc[12],So3=acc[13];
    float d0  = A0e-A0o;
    float dc1 = Ce1-Co1, ds1 = Se1-So1;
    float dc2 = Ce2-Co2, ds2 = Se2-So2;
    float dc3 = Ce3-Co3, ds3 = Se3-So3;
    float* gp = ghb + (isRow ? 1536 : 0);
    const int k = idx;
    gp[(0*2+0)*128+k] = dc3*INV_SQRT128;  gp[(0*2+1)*128+k] =  ds3*INV_SQRT128;
    gp[(1*2+0)*128+k] = dc2*INV_SQRT128;  gp[(1*2+1)*128+k] =  ds2*INV_SQRT128;
    gp[(2*2+0)*128+k] = dc1*INV_SQRT128;  gp[(2*2+1)*128+k] =  ds1*INV_SQRT128;
    gp[(3*2+0)*128+k] = d0 *INV_SQRT128;  gp[(3*2+1)*128+k] =  0.f;
    gp[(4*2+0)*128+k] = dc1*INV_SQRT128;  gp[(4*2+1)*128+k] = -ds1*INV_SQRT128;
    gp[(5*2+0)*128+k] = dc2*INV_SQRT128;  gp[(5*2+1)*128+k] = -ds2*INV_SQRT128;
    if (isRow){
      smem[SM_HLR + 0*128 + k] = A0e+A0o;
      smem[SM_HLR + 1*128 + k] = Ce1+Co1;
      smem[SM_HLR + 2*128 + k] = Ce2+Co2;
      smem[SM_HLR + 3*128 + k] = Ce3+Co3;
      smem[SM_HLI + 0*128 + k] = -(Se1+So1);
      smem[SM_HLI + 1*128 + k] = -(Se2+So2);
      smem[SM_HLI + 2*128 + k] = -(Se3+So3);
    } else {
      smem[SM_GG + (0*2+0)*128 + k] = dc3;  smem[SM_GG + (0*2+1)*128 + k] = ds3;
      smem[SM_GG + (1*2+0)*128 + k] = dc2;  smem[SM_GG + (1*2+1)*128 + k] = ds2;
      smem[SM_GG + (2*2+0)*128 + k] = dc1;  smem[SM_GG + (2*2+1)*128 + k] = ds1;
      smem[SM_GG + (3*2+0)*128 + k] = d0;   smem[SM_GG + (3*2+1)*128 + k] = 0.f;
    }
  }
  __syncthreads();

  // ---- Fc tail: 36 outputs x 4 chunks ----
  if (tid < 144){
    int out = tid >> 2, chunk = tid & 3;
    int wi = out/6, zi = out%6, z = 61+zi;
    int wsrc = (wi<4) ? wi : (wi==4 ? 2 : 1);
    float isg = (wi<4) ? 1.f : -1.f;
    float fR=0.f, fI=0.f;
    const int cEnd = chunk*32 + 32;
    for (int c=chunk*32; c<cEnd; ++c){
      float gR = smem[SM_GG + (wsrc*2  )*128 + c];
      float gI = isg*smem[SM_GG + (wsrc*2+1)*128 + c];
      int m = (z*c) & 127;
      float ts, tc; __sincosf((float)m*C128, &ts, &tc);
      fR += gR*tc + gI*ts;
      fI += gI*tc - gR*ts;
    }
    fR += __shfl_xor(fR,1); fI += __shfl_xor(fI,1);
    fR += __shfl_xor(fR,2); fI += __shfl_xor(fI,2);
    if (chunk==0){
      ghb[3072 + out*2]     = fR * INV128;
      ghb[3072 + out*2 + 1] = fI * INV128;
    }
  }
  // ---- magC tail: 49 outputs x 4 chunks ----
  if (tid >= 256 && tid < 452){
    int i = (tid-256) >> 2, chunk = (tid-256) & 3;
    int u = i/7 - 3, v = i%7 - 3;
    int va = v < 0 ? -v : v;
    float vsg = v < 0 ? -1.f : 1.f;
    float fR=0.f, fI=0.f;
    const int rEnd = chunk*32 + 32;
    for (int r=chunk*32; r<rEnd; ++r){
      float hR = smem[SM_HLR + va*128 + r];
      float hI = (va==0) ? 0.f : vsg*smem[SM_HLI + (va-1)*128 + r];
      int m = ((u*r) % 128 + 128) & 127;
      float ts, tc; __sincosf((float)m*C128, &ts, &tc);
      fR += hR*tc + hI*ts;
      fI += hI*tc - hR*ts;
    }
    fR += __shfl_xor(fR,1); fI += __shfl_xor(fI,1);
    fR += __shfl_xor(fR,2); fI += __shfl_xor(fI,2);
    if (chunk==0){
      fR *= INV128; fI *= INV128;
      ghb[3144 + i] = sqrtf(fR*fR + fI*fI);
    }
  }
}

// =====================================================================
// K_mlp
// =====================================================================
__global__ void __launch_bounds__(64) K_mlp(const float* __restrict__ GH,
                                            const float* __restrict__ w1,
                                            const float* __restrict__ b1,
                                            const float* __restrict__ w2,
                                            const float* __restrict__ b2,
                                            float* __restrict__ kern){
  __shared__ float flat[49];
  __shared__ float hh[32];
  const int b = blockIdx.x, tid = threadIdx.x;
  if (tid < 49){
    float s = 0.f;
    for (int c=0; c<256; ++c)
      s += GH[(size_t)(b*256 + c)*GH_STRIDE + 3144 + tid];
    flat[tid] = s * (1.0f/256.0f);
  }
  __syncthreads();
  if (tid < 32){
    float s = b1[tid];
    for (int i=0; i<49; ++i) s += flat[i]*w1[tid*49+i];
    hh[tid] = fmaxf(s, 0.f);
  }
  __syncthreads();
  if (tid == 0){
    float p[3];
    #pragma unroll
    for (int k=0; k<3; ++k){
      float s = b2[k];
      for (int j=0; j<32; ++j) s += hh[j]*w2[k*32+j];
      p[k] = s;
    }
    float theta = atan2f(p[0], p[1])*0.5f + 1.57079632679489662f;
    float ct = cosf(theta), st = sinf(theta);
    float l1 = expf(p[2]);
    float l2 = 1.0f/(l1 + 1e-8f);
    float inv1 = 1.0f/(2.0f*l1*l1);
    float inv2 = 1.0f/(2.0f*l2*l2);
    float sum = 0.f;
    for (int i=0; i<7; ++i) for (int j=0; j<7; ++j){
      float yy = (float)(i-3), xx = (float)(j-3);
      float xr =  xx*ct + yy*st;
      float yr = -xx*st + yy*ct;
      sum += expf(-(xr*xr*inv1 + yr*yr*inv2));
    }
    float inv = 1.0f/(sum + 1e-8f);
    for (int i=0; i<7; ++i) for (int j=0; j<7; ++j){
      float yy = (float)(i-3), xx = (float)(j-3);
      float xr =  xx*ct + yy*st;
      float yr = -xx*st + yy*ct;
      kern[b*49 + i*7 + j] = expf(-(xr*xr*inv1 + yr*yr*inv2)) * inv;
    }
  }
}

// =====================================================================
// K3: per batch: kappa/lambda tables + W field
// =====================================================================
__global__ void __launch_bounds__(256) K3(const float* __restrict__ kern,
                                          float* __restrict__ KL,
                                          float* __restrict__ W){
  __shared__ float twc[128], tws[128], kl[49];
  __shared__ float kapl[7][2][128];
  const int b = blockIdx.x, tid = threadIdx.x;
  if (tid < 128){
    float s,c; __sincosf((float)tid*C128, &s, &c);
    twc[tid]=c; tws[tid]=s;
  }
  if (tid < 49) kl[tid] = kern[b*49 + tid];
  __syncthreads();
  if (tid < 128){
    const int c = tid;
    float* klb = KL + (size_t)b*3584;
    #pragma unroll
    for (int dp=0; dp<7; ++dp){
      float kR=0.f, kI=0.f;
      #pragma unroll
      for (int dq=0; dq<7; ++dq){
        int m = (((dq-3)*c) % 128 + 128) & 127;
        float kv = kl[dp*7+dq];
        kR += kv*twc[m]; kI -= kv*tws[m];
      }
      klb[(dp*2  )*128 + c] = kR;
      klb[(dp*2+1)*128 + c] = kI;
      kapl[dp][0][c] = kR; kapl[dp][1][c] = kI;
    }
    const int r = tid;
    #pragma unroll
    for (int dq=0; dq<7; ++dq){
      float lR=0.f, lI=0.f;
      #pragma unroll
      for (int dp=0; dp<7; ++dp){
        int m = (((dp-3)*r) % 128 + 128) & 127;
        float kv = kl[dp*7+dq];
        lR += kv*twc[m]; lI -= kv*tws[m];
      }
      klb[1792 + (dq*2  )*128 + r] = lR;
      klb[1792 + (dq*2+1)*128 + r] = lI;
    }
  }
  __syncthreads();
  for (int k=0;k<64;++k){
    int px = k*256 + tid;
    int r = px >> 7, c = px & 127;
    float w = 0.f;
    #pragma unroll
    for (int dp=0; dp<7; ++dp){
      int m = (((dp-3)*r) % 128 + 128) & 127;
      w += twc[m]*kapl[dp][0][c] + tws[m]*kapl[dp][1][c];
    }
    W[(size_t)b*IMG + px] = w;
  }
}

// =====================================================================
// K_tab: per image: Abar (corner-folded) and Bbar tables
// =====================================================================
__global__ void __launch_bounds__(128) K_tab(const float* __restrict__ GH,
                                             const float* __restrict__ KL,
                                             const float* __restrict__ kern,
                                             float* __restrict__ AB){
  __shared__ float dRe[36], dIm[36], kl[49];
  const int tid = threadIdx.x;
  const int img = blockIdx.x, b = img >> 8;
  const float* ghb = GH + (size_t)img*GH_STRIDE;
  const float* klb = KL + (size_t)b*3584;
  float* abb = AB + (size_t)img*AB_STRIDE;

  if (tid < 49) kl[tid] = kern[b*49 + tid];
  __syncthreads();
  if (tid < 36){
    int si = tid/6, ti = tid%6;
    float dR=0.f, dI=0.f;
    for (int j=0; j<c_pcnt[si]; ++j){
      int dp = c_pdp0[si] + j;
      int wi = (si-3) + dp;
      for (int l=0; l<c_pcnt[ti]; ++l){
        int dq = c_pdp0[ti] + l;
        int zi = (ti-3) + dq;
        float kv = kl[dp*7+dq];
        dR += kv * ghb[3072 + (wi*6+zi)*2];
        dI += kv * ghb[3072 + (wi*6+zi)*2 + 1];
      }
    }
    dRe[tid] = dR; dIm[tid] = dI;
  }
  __syncthreads();

  const int c = tid;
  float s1,c1; __sincosf((float)c*C128, &s1, &c1);
  float c2 = c1*c1 - s1*s1, s2 = 2.f*c1*s1;
  float c3 = c1*c2 - s1*s2, s3 = s1*c2 + c1*s2;
  float ct[6] = {c3,c2,c1,1.f,c1,c2};
  float st[6] = {-s3,-s2,-s1,0.f,s1,s2};
  float sgnc = (c & 1) ? -1.f : 1.f;

  float gr[6], gi[6], kr[7], ki[7];
  #pragma unroll
  for (int w=0;w<6;++w){ gr[w]=ghb[(w*2)*128+c]; gi[w]=ghb[(w*2+1)*128+c]; }
  #pragma unroll
  for (int dp=0;dp<7;++dp){ kr[dp]=klb[(dp*2)*128+c]; ki[dp]=klb[(dp*2+1)*128+c]; }

  #pragma unroll
  for (int si=0; si<6; ++si){
    float dR=0.f, dI=0.f;
    for (int j=0; j<c_pcnt[si]; ++j){
      int dp = c_pdp0[si] + j;
      int w = (si-3) + dp;
      dR += kr[dp]*gr[w] - ki[dp]*gi[w];
      dI += kr[dp]*gi[w] + ki[dp]*gr[w];
    }
    float corrR=0.f, corrI=0.f;
    #pragma unroll
    for (int ti=0; ti<6; ++ti){
      float DR = dRe[si*6+ti], DI = dIm[si*6+ti];
      corrR += DR*ct[ti] - DI*st[ti];
      corrI += DR*st[ti] + DI*ct[ti];
    }
    abb[(si*2  )*128 + c] = INV_SQRT128*dR - INV128*sgnc*corrR;
    abb[(si*2+1)*128 + c] = INV_SQRT128*dI - INV128*sgnc*corrI;
  }

  const int r = tid;
  float hr[6], hi_[6], lr[7], li[7];
  #pragma unroll
  for (int z=0;z<6;++z){ hr[z]=ghb[1536+(z*2)*128+r]; hi_[z]=ghb[1536+(z*2+1)*128+r]; }
  #pragma unroll
  for (int dq=0;dq<7;++dq){ lr[dq]=klb[1792+(dq*2)*128+r]; li[dq]=klb[1792+(dq*2+1)*128+r]; }
  #pragma unroll
  for (int ti=0; ti<6; ++ti){
    float bR=0.f, bI=0.f;
    for (int l=0; l<c_pcnt[ti]; ++l){
      int dq = c_pdp0[ti] + l;
      int z = (ti-3) + dq;
      bR += lr[dq]*hr[z] - li[dq]*hi_[z];
      bI += lr[dq]*hi_[z] + li[dq]*hr[z];
    }
    abb[1536 + r*12 + ti*2]     = INV_SQRT128*bR;
    abb[1536 + r*12 + ti*2 + 1] = INV_SQRT128*bI;
  }
}

// =====================================================================
// K4: per image: filt = x*W - E  (bf16 out), float2 per lane
// =====================================================================
__global__ void __launch_bounds__(256) K4(const float* __restrict__ xlow,
                                          const float* __restrict__ W,
                                          const float* __restrict__ AB,
                                          unsigned short* __restrict__ filt){
  const int tid = threadIdx.x;
  const int img = blockIdx.x, b = img >> 8;
  const int c0 = (tid & 63)*2, grp = tid >> 6;
  const float* abb = AB + (size_t)img*AB_STRIDE;
  const float* xim = xlow + (size_t)img*IMG;
  const float* Wb  = W + (size_t)b*IMG;
  unsigned short* fim = filt + (size_t)img*IMG;

  float ar[2][6], ai[2][6], ctc[2][6], stc[2][6];
  #pragma unroll
  for (int col=0; col<2; ++col){
    int c = c0 + col;
    #pragma unroll
    for (int si=0;si<6;++si){ ar[col][si]=abb[(si*2)*128+c]; ai[col][si]=abb[(si*2+1)*128+c]; }
    float s1,c1; __sincosf((float)c*C128, &s1, &c1);
    float c2 = c1*c1 - s1*s1, s2 = 2.f*c1*s1;
    float c3 = c1*c2 - s1*s2, s3 = s1*c2 + c1*s2;
    ctc[col][0]=c3; ctc[col][1]=c2; ctc[col][2]=c1; ctc[col][3]=1.f; ctc[col][4]=c1; ctc[col][5]=c2;
    stc[col][0]=-s3; stc[col][1]=-s2; stc[col][2]=-s1; stc[col][3]=0.f; stc[col][4]=s1; stc[col][5]=s2;
  }

  for (int k=0;k<32;++k){
    int ru = __builtin_amdgcn_readfirstlane(grp*32 + k);
    const float* brow = abb + 1536 + ru*12;
    float4 b0 = *(const float4*)(brow);
    float4 b1 = *(const float4*)(brow+4);
    float4 b2 = *(const float4*)(brow+8);
    float rs1,rc1; __sincosf((float)ru*C128, &rs1, &rc1);
    float rc2 = rc1*rc1 - rs1*rs1, rs2 = 2.f*rc1*rs1;
    float rc3 = rc1*rc2 - rs1*rs2, rs3 = rs1*rc2 + rc1*rs2;
    float rcs[6] = {rc3,rc2,rc1,1.f,rc1,rc2};
    float rss[6] = {-rs3,-rs2,-rs1,0.f,rs1,rs2};

    float ER0 = 0.f, ER1 = 0.f;
    #pragma unroll
    for (int si=0;si<6;++si){
      ER0 += rcs[si]*ar[0][si] - rss[si]*ai[0][si];
      ER1 += rcs[si]*ar[1][si] - rss[si]*ai[1][si];
    }
    float rsg = (ru & 1) ? -1.f : 1.f;
    ER0 *= rsg; ER1 *= rsg;

    float bRv[6] = {b0.x, b0.z, b1.x, b1.z, b2.x, b2.z};
    float bIv[6] = {b0.y, b0.w, b1.y, b1.w, b2.y, b2.w};
    float EC0 = 0.f, EC1 = 0.f;
    #pragma unroll
    for (int ti=0;ti<6;++ti){
      EC0 += ctc[0][ti]*bRv[ti] - stc[0][ti]*bIv[ti];
      EC1 += ctc[1][ti]*bRv[ti] - stc[1][ti]*bIv[ti];
    }
    int px = ru*128 + c0;
    float2 xv = *(const float2*)(&xim[px]);
    float2 wv = *(const float2*)(&Wb[px]);
    float v0 = xv.x*wv.x - ER0 - EC0;
    float v1 = xv.y*wv.y - ER1 + EC1;
    unsigned int pack = ((unsigned int)f2bf(v1) << 16) | (unsigned int)f2bf(v0);
    *(unsigned int*)(&fim[px]) = pack;
  }
}

// =====================================================================
// K_w: refine_w f32 -> bf16
// =====================================================================
__global__ void __launch_bounds__(256) K_w(const float* __restrict__ rw,
                                           unsigned short* __restrict__ rwbf){
  int i = blockIdx.x*256 + threadIdx.x;
  rwbf[i] = f2bf(rw[i]);
}

// =====================================================================
// K_up: bilinear upsample x_high (64x64 -> 128x128) as bf16
// =====================================================================
__global__ void __launch_bounds__(256) K_up(const float* __restrict__ xhigh,
                                            unsigned short* __restrict__ up){
  __shared__ float xs[64*68];
  const int tid = threadIdx.x;
  const int img = blockIdx.x;
  const float* src = xhigh + (size_t)img*4096;
  unsigned short* dst = up + (size_t)img*IMG;

  #pragma unroll
  for (int p=0; p<4; ++p){
    int t = p*256 + tid;
    float4 v = ((const float4*)src)[t];
    int r = t >> 4, k = t & 15;
    *(float4*)(&xs[r*68 + k*4]) = v;
  }
  __syncthreads();

  for (int k=0; k<32; ++k){
    int pr = k*256 + tid;
    int y = pr >> 6, x0 = (pr & 63)*2;
    float fy = 0.5f*(float)y - 0.25f;
    int iyf = (int)floorf(fy);
    float ty = fy - (float)iyf;
    int iy0 = iyf < 0 ? 0 : iyf;
    int iy1 = (iyf+1) > 63 ? 63 : (iyf+1);
    float wy1 = ty, wy0 = 1.0f - ty;
    const float* r0 = &xs[iy0*68];
    const float* r1 = &xs[iy1*68];

    float outv[2];
    #pragma unroll
    for (int e=0; e<2; ++e){
      int x = x0 + e;
      float fx = 0.5f*(float)x - 0.25f;
      int ixf = (int)floorf(fx);
      float tx = fx - (float)ixf;
      int ix0 = ixf < 0 ? 0 : ixf;
      int ix1 = (ixf+1) > 63 ? 63 : (ixf+1);
      float wx1 = tx, wx0 = 1.0f - tx;
      outv[e] = wy0*(wx0*r0[ix0] + wx1*r0[ix1])
              + wy1*(wx0*r1[ix0] + wx1*r1[ix1]);
    }
    unsigned int pack = ((unsigned int)f2bf(outv[1]) << 16) | (unsigned int)f2bf(outv[0]);
    *(unsigned int*)(&dst[y*NW + x0]) = pack;
  }
}

// =====================================================================
// K_trans: filt [b][c][p] -> filtT [b][p][c], 64x64 tiles, ushort4 I/O
// =====================================================================
__global__ void __launch_bounds__(256) K_trans(const unsigned short* __restrict__ in,
                                               unsigned short* __restrict__ outT){
  __shared__ unsigned short tile[64*68];    // [p][c], stride 68
  const int p0 = blockIdx.x * 64;
  const int c0 = blockIdx.y * 64;
  const int b  = blockIdx.z;
  const int tid = threadIdx.x;
  const int lo = tid >> 4;          // 0..15
  const int q4 = (tid & 15) * 4;    // 0..60

  #pragma unroll
  for (int pass=0; pass<4; ++pass){
    int cc = lo + pass*16;
    ushort4 v = *(const ushort4*)(&in[((size_t)b*NC + c0 + cc)*IMG + p0 + q4]);
    tile[(q4+0)*68 + cc] = v.x;
    tile[(q4+1)*68 + cc] = v.y;
    tile[(q4+2)*68 + cc] = v.z;
    tile[(q4+3)*68 + cc] = v.w;
  }
  __syncthreads();
  #pragma unroll
  for (int pass=0; pass<4; ++pass){
    int pp = lo + pass*16;
    ushort4 v = *(const ushort4*)(&tile[pp*68 + q4]);
    *(ushort4*)(&outT[((size_t)b*IMG + p0 + pp)*NC + c0 + q4]) = v;
  }
}

// =====================================================================
// K_gemm: out[b,o,p] = sum_c rw[o,c]*filt[b,c,p] + up[b,o,p]
// Double-buffered LDS, 1 barrier per K-step. XCD-paired grid.
// =====================================================================
__global__ void __launch_bounds__(256) K_gemm(const unsigned short* __restrict__ rwbf,
                                              const unsigned short* __restrict__ filtT,
                                              const unsigned short* __restrict__ up,
                                              float* __restrict__ out){
  __shared__ unsigned short At[2][128*32];
  __shared__ unsigned short Bt[2][128*32];
  const int tid = threadIdx.x, lane = tid & 63, wv = tid >> 6;
  const int wr = wv >> 1, wc = wv & 1;
  const int xg = blockIdx.x;
  const int g16 = xg >> 4, i16 = xg & 15;
  const int ot = i16 >> 3, pt = (g16 << 3) | (i16 & 7);
  const int b = blockIdx.z;
  const int p0 = pt*128, o0 = ot*128;

  f32x4 acc[4][4];
  #pragma unroll
  for (int m=0;m<4;++m)
    #pragma unroll
    for (int n=0;n<4;++n){ f32x4 z = {0.f,0.f,0.f,0.f}; acc[m][n] = z; }

  const int row  = tid >> 2;
  const int koff = (tid & 3) * 8;
  const unsigned short* aP0 = &rwbf[(size_t)(o0+row   )*256 + koff];
  const unsigned short* aP1 = &rwbf[(size_t)(o0+row+64)*256 + koff];
  const unsigned short* bP0 = &filtT[((size_t)b*IMG + p0+row   )*256 + koff];
  const unsigned short* bP1 = &filtT[((size_t)b*IMG + p0+row+64)*256 + koff];

  i32x4 av0 = *(const i32x4*)(aP0);
  i32x4 av1 = *(const i32x4*)(aP1);
  i32x4 bv0 = *(const i32x4*)(bP0);
  i32x4 bv1 = *(const i32x4*)(bP1);
  *(i32x4*)(&At[0][ row     *32 + koff]) = av0;
  *(i32x4*)(&At[0][(row+64) *32 + koff]) = av1;
  *(i32x4*)(&Bt[0][ row     *32 + koff]) = bv0;
  *(i32x4*)(&Bt[0][(row+64) *32 + koff]) = bv1;
  __syncthreads();

  const int g = lane >> 4, r16 = lane & 15;
  for (int ks=0; ks<8; ++ks){
    const int cur = ks & 1;
    if (ks < 7){
      const int k0 = (ks+1)*32;
      av0 = *(const i32x4*)(aP0 + k0);
      av1 = *(const i32x4*)(aP1 + k0);
      bv0 = *(const i32x4*)(bP0 + k0);
      bv1 = *(const i32x4*)(bP1 + k0);
    }
    bf16x8 af[4], bfr[4];
    #pragma unroll
    for (int m=0;m<4;++m) af[m]  = *(const bf16x8*)(&At[cur][(wr*64 + m*16 + r16)*32 + g*8]);
    #pragma unroll
    for (int n=0;n<4;++n) bfr[n] = *(const bf16x8*)(&Bt[cur][(wc*64 + n*16 + r16)*32 + g*8]);
    #pragma unroll
    for (int m=0;m<4;++m)
      #pragma unroll
      for (int n=0;n<4;++n)
        acc[m][n] = __builtin_amdgcn_mfma_f32_16x16x32_bf16(af[m], bfr[n], acc[m][n], 0, 0, 0);
    if (ks < 7){
      const int nxt = cur ^ 1;
      *(i32x4*)(&At[nxt][ row     *32 + koff]) = av0;
      *(i32x4*)(&At[nxt][(row+64) *32 + koff]) = av1;
      *(i32x4*)(&Bt[nxt][ row     *32 + koff]) = bv0;
      *(i32x4*)(&Bt[nxt][(row+64) *32 + koff]) = bv1;
      __syncthreads();
    }
  }

  const int y = pt;
  #pragma unroll
  for (int m=0;m<4;++m){
    #pragma unroll
    for (int j=0;j<4;++j){
      int o = o0 + wr*64 + m*16 + g*4 + j;
      size_t base = (size_t)(b*NC + o)*IMG + (size_t)y*NW;
      #pragma unroll
      for (int n=0;n<4;++n){
        int xcol = wc*64 + n*16 + r16;
        float upv = bf2f(up[base + xcol]);
        out[base + xcol] = acc[m][n][j] + upv;
      }
    }
  }
}

// =====================================================================
extern "C" void kernel_launch(void* const* d_in, const int* in_sizes, int n_in,
                              void* d_out, int out_size, void* d_ws, size_t ws_size,
                              hipStream_t stream){
  (void)in_sizes; (void)n_in; (void)out_size; (void)ws_size;
  const float* xhigh = (const float*)d_in[0];
  const float* xlow  = (const float*)d_in[1];
  const float* w1    = (const float*)d_in[2];
  const float* b1    = (const float*)d_in[3];
  const float* w2    = (const float*)d_in[4];
  const float* b2    = (const float*)d_in[5];
  const float* rw    = (const float*)d_in[6];

  char* ws = (char*)d_ws;
  unsigned short* filt  = (unsigned short*)(ws);                    // 67,108,864
  unsigned short* filtT = (unsigned short*)(ws + 67108864);         // 67,108,864
  float* GH   = (float*)(ws + 134217728);                           // 26,214,400
  float* AB   = (float*)(ws + 160432128);                           // 25,165,824
  float* kern = (float*)(ws + 185597952);                           // 4,096 (pad)
  float* KL   = (float*)(ws + 185602048);                           // 114,688
  float* Wf   = (float*)(ws + 185716736);                           // 524,288
  unsigned short* rwbf = (unsigned short*)(ws + 186241024);         // 131,072
  unsigned short* up   = filt;   // reuse: filt is dead after K_trans

  K1   <<<NIMG, 512, 0, stream>>>(xlow, GH);
  K_mlp<<<NB,   64,  0, stream>>>(GH, w1, b1, w2, b2, kern);
  K3   <<<NB,   256, 0, stream>>>(kern, KL, Wf);
  K_w  <<<256,  256, 0, stream>>>(rw, rwbf);
  K_tab<<<NIMG, 128, 0, stream>>>(GH, KL, kern, AB);
  K4   <<<NIMG, 256, 0, stream>>>(xlow, Wf, AB, filt);
  K_trans<<<dim3(256, 4, NB), 256, 0, stream>>>(filt, filtT);
  K_up <<<NIMG, 256, 0, stream>>>(xhigh, up);
  K_gemm <<<dim3(256, 1, NB), 256, 0, stream>>>(rwbf, filtT, up, (float*)d_out);
}